// Round 4
// baseline (1668.887 us; speedup 1.0000x reference)
//
#include <hip/hip_runtime.h>
#include <hip/hip_bf16.h>

// ---------------------------------------------------------------------------
// Recommender pipeline, f32 compute.
//  K0 detect : bf16-vs-f32 flag in ws[0]
//  K1 prep   : weights -> f32 in ws; GEMM weights K-PACKED [k/4][128][4]
//  K2 news   : news_e = tanh(elu(title@W1^T+b)@W2^T+b)        [3520,128]
//  K3 gather : X[n] = [ent[node], sum_k(ent[adj]+rel[radj])]  [70400,256]
//  K4 anchor : FUSED tanh-GEMM + logits + softmax -> AE
//              R0-R3 post-mortem: every variant kept the per-lane WEIGHT
//              loads (2x1KB per k4) in the inner loop from L2 -> all pinned
//              at 176-213us, VALUBusy ~55-60% (latency-limited, not pipe-
//              saturated). R4: canonical global->LDS double-buffered chunk
//              pipeline for BOTH W and X. Inner loop = pure DS+VALU (2
//              ds_read_b128 W + 10 broadcast X + 80 FMA per k4); staging
//              loads issued-early to regs, ds_write late, one barrier per
//              chunk. Stage C reuses the W double-buffer for Waw1.
//  K5 mlp    : elu(elu([news_e,AE]@Wm1^T+b)@Wm2^T+b)          [3520,128]
//  K6 score  : user mean + dot                                 [64,5]
// ---------------------------------------------------------------------------

#define B_ 64
#define S_ 5
#define UC_ 50
#define A_ 20
#define NCAND 320
#define NCLK 3200
#define NNEWS 3520
#define NANCH 70400

// ws layout (float indices)
static constexpr long OFF_WNC1P = 64;        // [192][128][4]
static constexpr long OFF_BNC1  = 98368;
static constexpr long OFF_WNC2P = 98496;     // [32][128][4]
static constexpr long OFF_BNC2  = 114880;
static constexpr long OFF_WANCP = 115008;    // [64][128][4]
static constexpr long OFF_BANC  = 147776;
static constexpr long OFF_WAW1P = 147904;    // [32][128][4]
static constexpr long OFF_BAW1  = 164288;
static constexpr long OFF_WAW2  = 164416;    // [128]
static constexpr long OFF_BAW2  = 164544;    // [1]
static constexpr long OFF_WM1P  = 164548;    // [64][128][4]
static constexpr long OFF_BM1   = 197316;
static constexpr long OFF_WM2P  = 197444;    // [32][128][4]
static constexpr long OFF_BM2   = 213828;
static constexpr long OFF_REL   = 213956;    // [100][128]
static constexpr long OFF_AE    = 226756;    // [3520][128]
static constexpr long OFF_NE    = 677316;    // [3520][128]
static constexpr long OFF_MO    = 1127876;   // [3520][128]
static constexpr long OFF_X     = 1578436;   // [70400][256]
// total ~19.6M floats = 78.4 MB

__device__ __forceinline__ float ldf(const void* p, long i, int bf) {
  if (bf) {
    unsigned int u = (unsigned int)((const unsigned short*)p)[i];
    u <<= 16;
    return __uint_as_float(u);
  }
  return ((const float*)p)[i];
}

// 4 consecutive elems starting at i (i % 4 == 0)
__device__ __forceinline__ float4 ldf4(const void* p, long i, int bf) {
  float4 f;
  if (bf) {
    const unsigned short* q = (const unsigned short*)p + i;
    uint2 u = *(const uint2*)q;
    f.x = __uint_as_float(u.x << 16);
    f.y = __uint_as_float(u.x & 0xffff0000u);
    f.z = __uint_as_float(u.y << 16);
    f.w = __uint_as_float(u.y & 0xffff0000u);
  } else {
    f = *(const float4*)((const float*)p + i);
  }
  return f;
}

__device__ __forceinline__ float eluf(float v) { return v > 0.f ? v : expm1f(v); }

// ---- K0: dtype detect -----------------------------------------------------
__global__ void k_detect(const void* ent, int* flag) {
  __shared__ int cnt;
  if (threadIdx.x == 0) cnt = 0;
  __syncthreads();
  unsigned short u = ((const unsigned short*)ent)[threadIdx.x];
  int e = (u >> 7) & 0xFF;
  int ok = (e >= 107 && e <= 146) ? 1 : 0;
  atomicAdd(&cnt, ok);
  __syncthreads();
  if (threadIdx.x == 0) *flag = (cnt >= 200) ? 1 : 0;
}

// ---- K1: convert weights; GEMM weights K-packed ---------------------------
__global__ __launch_bounds__(256) void k_prep(
    const void* s0, const void* s1, const void* s2, const void* s3,
    const void* s4, const void* s5, const void* s6, const void* s7,
    const void* s8, const void* s9, const void* s10, const void* s11,
    const void* s12, const void* s13, const void* s14, float* ws) {
  const int bf = ((const int*)ws)[0];
  const void* srcs[15] = {s0,s1,s2,s3,s4,s5,s6,s7,s8,s9,s10,s11,s12,s13,s14};
  const int R[15] = {128,128,128,128,128,128,128,128,1,  1,  128,128,128,128,100};
  const int C[15] = {768,1,  128,1,  256,1,  128,1,  128,1,  256,1,  128,1,  128};
  const int MD[15]= {2,  0,  2,  0,  2,  0,  2,  0,  0,  0,  2,  0,  2,  0,  0};
  const long OFF[15] = {OFF_WNC1P,OFF_BNC1,OFF_WNC2P,OFF_BNC2,OFF_WANCP,OFF_BANC,
                        OFF_WAW1P,OFF_BAW1,OFF_WAW2,OFF_BAW2,OFF_WM1P,OFF_BM1,
                        OFF_WM2P,OFF_BM2,OFF_REL};
  const long total = 226689;
  for (long idx = (long)blockIdx.x * blockDim.x + threadIdx.x; idx < total;
       idx += (long)gridDim.x * blockDim.x) {
    long rem = idx;
    int s = 0;
    while (rem >= (long)R[s] * C[s]) { rem -= (long)R[s] * C[s]; s++; }
    float v = ldf(srcs[s], rem, bf);
    if (MD[s] == 2) {
      long r = rem / C[s], c = rem - r * C[s];
      ws[OFF[s] + (c >> 2) * 512 + r * 4 + (c & 3)] = v;
    } else {
      ws[OFF[s] + rem] = v;
    }
  }
}

// ---- K2: news title MLP (128 thr, 8 rows, acc[8]) ------------------------
__global__ __launch_bounds__(128) void k_news(const void* titles, const int* cand,
                                              const int* clk, float* ws) {
  const int bf = ((const int*)ws)[0];
  __shared__ __align__(16) float t[8][768];
  __shared__ __align__(16) float h1[8][128];
  int tid = threadIdx.x;
  long r0 = (long)blockIdx.x * 8;
  for (int x = tid * 4; x < 8 * 768; x += 128 * 4) {
    int c = x / 768, k = x - c * 768;
    long i = r0 + c;
    int id = (i < NCAND) ? cand[i] : clk[i - NCAND];
    *(float4*)&t[c][k] = ldf4(titles, (long)id * 768 + k, bf);
  }
  __syncthreads();
  int j = tid;
  const float4* W1 = (const float4*)(ws + OFF_WNC1P);
  float acc[8];
#pragma unroll
  for (int c = 0; c < 8; c++) acc[c] = 0.f;
  for (int k4 = 0; k4 < 192; k4++) {
    float4 w = W1[k4 * 128 + j];
#pragma unroll
    for (int c = 0; c < 8; c++) {
      const float4 xv = *(const float4*)&t[c][k4 * 4];
      acc[c] += w.x * xv.x + w.y * xv.y + w.z * xv.z + w.w * xv.w;
    }
  }
  float b1 = ws[OFF_BNC1 + j];
#pragma unroll
  for (int c = 0; c < 8; c++) h1[c][j] = eluf(acc[c] + b1);
  __syncthreads();
  const float4* W2 = (const float4*)(ws + OFF_WNC2P);
  float a2[8];
#pragma unroll
  for (int c = 0; c < 8; c++) a2[c] = 0.f;
  for (int k4 = 0; k4 < 32; k4++) {
    float4 w = W2[k4 * 128 + j];
#pragma unroll
    for (int c = 0; c < 8; c++) {
      const float4 xv = *(const float4*)&h1[c][k4 * 4];
      a2[c] += w.x * xv.x + w.y * xv.y + w.z * xv.z + w.w * xv.w;
    }
  }
  float b2 = ws[OFF_BNC2 + j];
  float* NE = ws + OFF_NE;
#pragma unroll
  for (int c = 0; c < 8; c++) NE[(r0 + c) * 128 + j] = tanhf(a2[c] + b2);
}

// ---- K3: gather (split, high occupancy, float4 + shfl) --------------------
// 256 thr = 8 groups of 32 lanes; one anchor row per group
__global__ __launch_bounds__(256) void k_gather(const void* ent, const int* canda,
                                                const int* clka, const int* eadj,
                                                const int* radj, float* ws) {
  const int bf = ((const int*)ws)[0];
  int lane = threadIdx.x & 31;
  int grp = threadIdx.x >> 5;
  long n = (long)blockIdx.x * 8 + grp;
  int node = (n < (long)NCAND * A_) ? canda[n] : clka[n - (long)NCAND * A_];
  int idx = 0;
  if (lane < 10) idx = eadj[(long)node * 10 + lane];
  else if (lane < 20) idx = radj[(long)node * 10 + (lane - 10)];
  int an[10], rn[10];
#pragma unroll
  for (int k = 0; k < 10; k++) {
    an[k] = __shfl(idx, k, 32);
    rn[k] = __shfl(idx, k + 10, 32);
  }
  float4 x1 = ldf4(ent, (long)node * 128 + lane * 4, bf);
  const float* relf = ws + OFF_REL;
  float4 acc = {0.f, 0.f, 0.f, 0.f};
#pragma unroll
  for (int k = 0; k < 10; k++) {
    float4 e = ldf4(ent, (long)an[k] * 128 + lane * 4, bf);
    const float4 r = *(const float4*)&relf[(long)rn[k] * 128 + lane * 4];
    acc.x += e.x + r.x;
    acc.y += e.y + r.y;
    acc.z += e.z + r.z;
    acc.w += e.w + r.w;
  }
  float* X = ws + OFF_X;
  *(float4*)&X[n * 256 + lane * 4] = x1;
  *(float4*)&X[n * 256 + 128 + lane * 4] = acc;
}

// ---- K4: FUSED anchor GEMMs + softmax -------------------------------------
// block = 2 news (40 anchors), 256 threads, 4 waves x 10 rows.
// K chunked by 32 floats (8 k4). Per chunk both operands staged to LDS
// double buffers (W slab 16KB, X slab 2.5KB) via registers: global loads
// issued BEFORE the previous chunk's compute, ds_writes after it, one
// barrier per chunk. Inner loop is pure DS+VALU. Stage C (Waw1) reuses the
// same W double buffer; H operand is broadcast from LDS H.
__global__ __launch_bounds__(256, 2) void k_anchor(float* ws) {
  __shared__ __align__(16) float4 Wb[2][8][128];   // 32 KB (two 16KB bufs)
  __shared__ __align__(16) float4 Xb[2][40][8];    // 10 KB
  __shared__ __align__(16) float H[40][128];       // 20 KB
  __shared__ float LG[40];
  int tid = threadIdx.x;
  int lane = tid & 63, wv = tid >> 6;  // wv owns rows wv*10 .. wv*10+9

  const float4* WancP = (const float4*)(ws + OFF_WANCP);   // 8192 f4 (64 k4)
  const float4* Waw1P = (const float4*)(ws + OFF_WAW1P);   // 4096 f4 (32 k4)
  const float4* Xg = (const float4*)(ws + OFF_X) + (long)blockIdx.x * 40 * 64;

  float4 wr0, wr1, wr2, wr3;  // staged W regs (4 f4/thread = 16KB/block)
  float4 xr0, xr1;            // staged X regs (320 f4: tid<64 carries 2)

  // --- Stage B: H = tanh(X @ Wanc^T + b), 40x128, K=256, 8 chunks ---
  float acc[10][2];
#pragma unroll
  for (int r = 0; r < 10; r++) { acc[r][0] = 0.f; acc[r][1] = 0.f; }

  // prologue: load + write chunk 0
  {
    const float4* src = WancP;  // chunk 0
    wr0 = src[tid]; wr1 = src[tid + 256]; wr2 = src[tid + 512]; wr3 = src[tid + 768];
    { int row = tid >> 3, c8 = tid & 7; xr0 = Xg[row * 64 + c8]; }
    if (tid < 64) { int i = tid + 256, row = i >> 3, c8 = i & 7; xr1 = Xg[row * 64 + c8]; }
    Wb[0][tid >> 7][tid & 127] = wr0;
    Wb[0][(tid + 256) >> 7][(tid + 256) & 127] = wr1;
    Wb[0][(tid + 512) >> 7][(tid + 512) & 127] = wr2;
    Wb[0][(tid + 768) >> 7][(tid + 768) & 127] = wr3;
    Xb[0][tid >> 3][tid & 7] = xr0;
    if (tid < 64) { int i = tid + 256; Xb[0][i >> 3][i & 7] = xr1; }
  }
  __syncthreads();

  for (int c = 0; c < 8; c++) {
    int p = c & 1;
    if (c < 7) {  // issue next-chunk loads early (latency hides under compute)
      const float4* src = WancP + (c + 1) * 1024;
      wr0 = src[tid]; wr1 = src[tid + 256]; wr2 = src[tid + 512]; wr3 = src[tid + 768];
      { int row = tid >> 3, c8 = tid & 7; xr0 = Xg[row * 64 + (c + 1) * 8 + c8]; }
      if (tid < 64) { int i = tid + 256, row = i >> 3, c8 = i & 7; xr1 = Xg[row * 64 + (c + 1) * 8 + c8]; }
    }
#pragma unroll
    for (int k4 = 0; k4 < 8; k4++) {
      float4 wa = Wb[p][k4][lane];
      float4 wb2 = Wb[p][k4][lane + 64];
#pragma unroll
      for (int r = 0; r < 10; r++) {
        const float4 xv = Xb[p][wv * 10 + r][k4];
        acc[r][0] += wa.x * xv.x + wa.y * xv.y + wa.z * xv.z + wa.w * xv.w;
        acc[r][1] += wb2.x * xv.x + wb2.y * xv.y + wb2.z * xv.z + wb2.w * xv.w;
      }
    }
    if (c < 7) {  // write staged regs into the other buffer
      int q = p ^ 1;
      Wb[q][tid >> 7][tid & 127] = wr0;
      Wb[q][(tid + 256) >> 7][(tid + 256) & 127] = wr1;
      Wb[q][(tid + 512) >> 7][(tid + 512) & 127] = wr2;
      Wb[q][(tid + 768) >> 7][(tid + 768) & 127] = wr3;
      Xb[q][tid >> 3][tid & 7] = xr0;
      if (tid < 64) { int i = tid + 256; Xb[q][i >> 3][i & 7] = xr1; }
    }
    __syncthreads();
  }

  // epilogue: issue stage-C chunk-0 W loads, then write H, then stage chunk 0
  {
    wr0 = Waw1P[tid]; wr1 = Waw1P[tid + 256]; wr2 = Waw1P[tid + 512]; wr3 = Waw1P[tid + 768];
    float ba = ws[OFF_BANC + lane], bb = ws[OFF_BANC + lane + 64];
#pragma unroll
    for (int r = 0; r < 10; r++) {
      H[wv * 10 + r][lane] = tanhf(acc[r][0] + ba);
      H[wv * 10 + r][lane + 64] = tanhf(acc[r][1] + bb);
    }
    Wb[0][tid >> 7][tid & 127] = wr0;
    Wb[0][(tid + 256) >> 7][(tid + 256) & 127] = wr1;
    Wb[0][(tid + 512) >> 7][(tid + 512) & 127] = wr2;
    Wb[0][(tid + 768) >> 7][(tid + 768) & 127] = wr3;
  }
  __syncthreads();

  // --- Stage C: logits = elu(H@Waw1^T+b)@w2 + b2, K=128, 4 chunks ---
  {
    float ac2[10][2];
#pragma unroll
    for (int r = 0; r < 10; r++) { ac2[r][0] = 0.f; ac2[r][1] = 0.f; }
    for (int c = 0; c < 4; c++) {
      int p = c & 1;
      if (c < 3) {
        const float4* src = Waw1P + (c + 1) * 1024;
        wr0 = src[tid]; wr1 = src[tid + 256]; wr2 = src[tid + 512]; wr3 = src[tid + 768];
      }
#pragma unroll
      for (int k4 = 0; k4 < 8; k4++) {
        float4 wa = Wb[p][k4][lane];
        float4 wb2 = Wb[p][k4][lane + 64];
#pragma unroll
        for (int r = 0; r < 10; r++) {
          const float4 hv = *(const float4*)&H[wv * 10 + r][(c * 8 + k4) * 4];
          ac2[r][0] += wa.x * hv.x + wa.y * hv.y + wa.z * hv.z + wa.w * hv.w;
          ac2[r][1] += wb2.x * hv.x + wb2.y * hv.y + wb2.z * hv.z + wb2.w * hv.w;
        }
      }
      if (c < 3) {
        int q = p ^ 1;
        Wb[q][tid >> 7][tid & 127] = wr0;
        Wb[q][(tid + 256) >> 7][(tid + 256) & 127] = wr1;
        Wb[q][(tid + 512) >> 7][(tid + 512) & 127] = wr2;
        Wb[q][(tid + 768) >> 7][(tid + 768) & 127] = wr3;
      }
      __syncthreads();
    }
    float b1a = ws[OFF_BAW1 + lane], b1b = ws[OFF_BAW1 + lane + 64];
    float w2a = ws[OFF_WAW2 + lane], w2b = ws[OFF_WAW2 + lane + 64];
    float bw2 = ws[OFF_BAW2];
#pragma unroll
    for (int r = 0; r < 10; r++) {
      float part = eluf(ac2[r][0] + b1a) * w2a + eluf(ac2[r][1] + b1b) * w2b;
#pragma unroll
      for (int o = 32; o > 0; o >>= 1) part += __shfl_down(part, o, 64);
      if (lane == 0) LG[wv * 10 + r] = part + bw2;
    }
  }
  __syncthreads();

  // --- Stage D: softmax over 20 anchors + weighted sum ---
  {
    int d = tid & 127, g = tid >> 7;
    float lg[20];
    float mx = -1e30f;
#pragma unroll
    for (int a = 0; a < 20; a++) { lg[a] = LG[g * 20 + a]; mx = fmaxf(mx, lg[a]); }
    float s = 0.f;
#pragma unroll
    for (int a = 0; a < 20; a++) { lg[a] = expf(lg[a] - mx); s += lg[a]; }
    float inv = 1.0f / s;
    float o = 0.f;
#pragma unroll
    for (int a = 0; a < 20; a++) o += lg[a] * H[g * 20 + a][d];
    float* AE = ws + OFF_AE;
    AE[((long)blockIdx.x * 2 + g) * 128 + d] = o * inv;
  }
}

// ---- K5: final MLP --------------------------------------------------------
__global__ __launch_bounds__(256) void k_mlp(float* ws) {
  __shared__ __align__(16) float xt[16][256];
  __shared__ __align__(16) float h1[16][128];
  int tid = threadIdx.x;
  long r0 = (long)blockIdx.x * 16;
  const float* NE = ws + OFF_NE;
  const float* AE = ws + OFF_AE;
  for (int x = tid; x < 16 * 256; x += 256) {
    int c = x >> 8, k = x & 255;
    xt[c][k] = (k < 128) ? NE[(r0 + c) * 128 + k] : AE[(r0 + c) * 128 + (k - 128)];
  }
  __syncthreads();
  int j = tid & 127, half = tid >> 7;
  const float4* W1 = (const float4*)(ws + OFF_WM1P);
  float acc[8];
#pragma unroll
  for (int c = 0; c < 8; c++) acc[c] = 0.f;
  for (int k4 = 0; k4 < 64; k4++) {
    float4 w = W1[k4 * 128 + j];
#pragma unroll
    for (int c = 0; c < 8; c++) {
      const float4 xv = *(const float4*)&xt[half * 8 + c][k4 * 4];
      acc[c] += w.x * xv.x + w.y * xv.y + w.z * xv.z + w.w * xv.w;
    }
  }
  float b1 = ws[OFF_BM1 + j];
#pragma unroll
  for (int c = 0; c < 8; c++) h1[half * 8 + c][j] = eluf(acc[c] + b1);
  __syncthreads();
  const float4* W2 = (const float4*)(ws + OFF_WM2P);
  float a2[8];
#pragma unroll
  for (int c = 0; c < 8; c++) a2[c] = 0.f;
  for (int k4 = 0; k4 < 32; k4++) {
    float4 w = W2[k4 * 128 + j];
#pragma unroll
    for (int c = 0; c < 8; c++) {
      const float4 xv = *(const float4*)&h1[half * 8 + c][k4 * 4];
      a2[c] += w.x * xv.x + w.y * xv.y + w.z * xv.z + w.w * xv.w;
    }
  }
  float b2 = ws[OFF_BM2 + j];
  float* MO = ws + OFF_MO;
#pragma unroll
  for (int c = 0; c < 8; c++) MO[(r0 + half * 8 + c) * 128 + j] = eluf(a2[c] + b2);
}

// ---- K6: user mean + scores ----------------------------------------------
__global__ __launch_bounds__(128) void k_score(const float* ws, void* out) {
  const int bf = ((const int*)ws)[0];
  int b = blockIdx.x;
  int d = threadIdx.x;
  const float* MO = ws + OFF_MO;
  float u = 0.f;
  for (int t = 0; t < UC_; t++) u += MO[(long)(NCAND + b * UC_ + t) * 128 + d];
  u *= (1.0f / UC_);
  __shared__ float red[2];
  for (int s = 0; s < S_; s++) {
    float p = MO[(long)(b * S_ + s) * 128 + d] * u;
#pragma unroll
    for (int o = 32; o > 0; o >>= 1) p += __shfl_down(p, o, 64);
    if ((d & 63) == 0) red[d >> 6] = p;
    __syncthreads();
    if (d == 0) {
      float v = red[0] + red[1];
      if (bf)
        ((__hip_bfloat16*)out)[b * S_ + s] = __float2bfloat16(v);
      else
        ((float*)out)[b * S_ + s] = v;
    }
    __syncthreads();
  }
}

extern "C" void kernel_launch(void* const* d_in, const int* in_sizes, int n_in,
                              void* d_out, int out_size, void* d_ws, size_t ws_size,
                              hipStream_t stream) {
  (void)in_sizes; (void)n_in; (void)out_size; (void)ws_size;
  const void* titles = d_in[0];
  const void* ent    = d_in[1];
  const void* rel    = d_in[2];
  const void* Wnc1 = d_in[3];  const void* bnc1 = d_in[4];
  const void* Wnc2 = d_in[5];  const void* bnc2 = d_in[6];
  const void* Wanc = d_in[7];  const void* banc = d_in[8];
  const void* Waw1 = d_in[9];  const void* baw1 = d_in[10];
  const void* Waw2 = d_in[11]; const void* baw2 = d_in[12];
  const void* Wm1  = d_in[13]; const void* bm1  = d_in[14];
  const void* Wm2  = d_in[15]; const void* bm2  = d_in[16];
  const int* cand  = (const int*)d_in[17];
  const int* clk   = (const int*)d_in[18];
  const int* canda = (const int*)d_in[19];
  const int* clka  = (const int*)d_in[20];
  const int* eadj  = (const int*)d_in[21];
  const int* radj  = (const int*)d_in[22];
  float* ws = (float*)d_ws;

  k_detect<<<1, 256, 0, stream>>>(ent, (int*)d_ws);
  k_prep<<<256, 256, 0, stream>>>(Wnc1, bnc1, Wnc2, bnc2, Wanc, banc, Waw1, baw1,
                                  Waw2, baw2, Wm1, bm1, Wm2, bm2, rel, ws);
  k_news<<<NNEWS / 8, 128, 0, stream>>>(titles, cand, clk, ws);
  k_gather<<<NANCH / 8, 256, 0, stream>>>(ent, canda, clka, eadj, radj, ws);
  k_anchor<<<NNEWS / 2, 256, 0, stream>>>(ws);
  k_mlp<<<NNEWS / 16, 256, 0, stream>>>(ws);
  k_score<<<B_, 128, 0, stream>>>(ws, d_out);
}

// Round 5
// 345.683 us; speedup vs baseline: 4.8278x; 4.8278x over previous
//
#include <hip/hip_runtime.h>
#include <hip/hip_bf16.h>

// ---------------------------------------------------------------------------
// Recommender pipeline, f32 compute.
//  K0 detect : bf16-vs-f32 flag in ws[0]
//  K1 prep   : weights -> f32 in ws; GEMM weights K-PACKED [k/4][128][4]
//  K2 news   : news_e = tanh(elu(title@W1^T+b)@W2^T+b)        [3520,128]
//  K3 gather : X[n] = [ent[node], sum_k(ent[adj]+rel[radj])]  [70400,256]
//  K4 anchor : FUSED tanh-GEMM + logits + softmax -> AE
//              R0-R4 post-mortem: all variants issued 10 broadcast X reads
//              per k4 per wave -> DS pipe (1/CU, ~12cy per ds_read_b128)
//              oversubscribed ~5x => 176us floor. R4's reg-staged W spilled
//              to scratch (6GB HBM). R5: half-wave split -- each 32-lane
//              half owns 5 rows x 128 cols (4 cols/lane), acc[5][4]:
//              5 broadcasts per k4 (2-way wave address diversity = free,
//              m136), 16 FMA per broadcast. Same split in stage C.
//              Bitwise-identical: per-(row,col) K-chains keep exact source
//              expression shape; logit reduce reproduces old 64-lane tree.
//  K5 mlp    : elu(elu([news_e,AE]@Wm1^T+b)@Wm2^T+b)          [3520,128]
//  K6 score  : user mean + dot                                 [64,5]
// ---------------------------------------------------------------------------

#define B_ 64
#define S_ 5
#define UC_ 50
#define A_ 20
#define NCAND 320
#define NCLK 3200
#define NNEWS 3520
#define NANCH 70400

// ws layout (float indices)
static constexpr long OFF_WNC1P = 64;        // [192][128][4]
static constexpr long OFF_BNC1  = 98368;
static constexpr long OFF_WNC2P = 98496;     // [32][128][4]
static constexpr long OFF_BNC2  = 114880;
static constexpr long OFF_WANCP = 115008;    // [64][128][4]
static constexpr long OFF_BANC  = 147776;
static constexpr long OFF_WAW1P = 147904;    // [32][128][4]
static constexpr long OFF_BAW1  = 164288;
static constexpr long OFF_WAW2  = 164416;    // [128]
static constexpr long OFF_BAW2  = 164544;    // [1]
static constexpr long OFF_WM1P  = 164548;    // [64][128][4]
static constexpr long OFF_BM1   = 197316;
static constexpr long OFF_WM2P  = 197444;    // [32][128][4]
static constexpr long OFF_BM2   = 213828;
static constexpr long OFF_REL   = 213956;    // [100][128]
static constexpr long OFF_AE    = 226756;    // [3520][128]
static constexpr long OFF_NE    = 677316;    // [3520][128]
static constexpr long OFF_MO    = 1127876;   // [3520][128]
static constexpr long OFF_X     = 1578436;   // [70400][256]
// total ~19.6M floats = 78.4 MB

__device__ __forceinline__ float ldf(const void* p, long i, int bf) {
  if (bf) {
    unsigned int u = (unsigned int)((const unsigned short*)p)[i];
    u <<= 16;
    return __uint_as_float(u);
  }
  return ((const float*)p)[i];
}

// 4 consecutive elems starting at i (i % 4 == 0)
__device__ __forceinline__ float4 ldf4(const void* p, long i, int bf) {
  float4 f;
  if (bf) {
    const unsigned short* q = (const unsigned short*)p + i;
    uint2 u = *(const uint2*)q;
    f.x = __uint_as_float(u.x << 16);
    f.y = __uint_as_float(u.x & 0xffff0000u);
    f.z = __uint_as_float(u.y << 16);
    f.w = __uint_as_float(u.y & 0xffff0000u);
  } else {
    f = *(const float4*)((const float*)p + i);
  }
  return f;
}

__device__ __forceinline__ float eluf(float v) { return v > 0.f ? v : expm1f(v); }

// ---- K0: dtype detect -----------------------------------------------------
__global__ void k_detect(const void* ent, int* flag) {
  __shared__ int cnt;
  if (threadIdx.x == 0) cnt = 0;
  __syncthreads();
  unsigned short u = ((const unsigned short*)ent)[threadIdx.x];
  int e = (u >> 7) & 0xFF;
  int ok = (e >= 107 && e <= 146) ? 1 : 0;
  atomicAdd(&cnt, ok);
  __syncthreads();
  if (threadIdx.x == 0) *flag = (cnt >= 200) ? 1 : 0;
}

// ---- K1: convert weights; GEMM weights K-packed ---------------------------
__global__ __launch_bounds__(256) void k_prep(
    const void* s0, const void* s1, const void* s2, const void* s3,
    const void* s4, const void* s5, const void* s6, const void* s7,
    const void* s8, const void* s9, const void* s10, const void* s11,
    const void* s12, const void* s13, const void* s14, float* ws) {
  const int bf = ((const int*)ws)[0];
  const void* srcs[15] = {s0,s1,s2,s3,s4,s5,s6,s7,s8,s9,s10,s11,s12,s13,s14};
  const int R[15] = {128,128,128,128,128,128,128,128,1,  1,  128,128,128,128,100};
  const int C[15] = {768,1,  128,1,  256,1,  128,1,  128,1,  256,1,  128,1,  128};
  const int MD[15]= {2,  0,  2,  0,  2,  0,  2,  0,  0,  0,  2,  0,  2,  0,  0};
  const long OFF[15] = {OFF_WNC1P,OFF_BNC1,OFF_WNC2P,OFF_BNC2,OFF_WANCP,OFF_BANC,
                        OFF_WAW1P,OFF_BAW1,OFF_WAW2,OFF_BAW2,OFF_WM1P,OFF_BM1,
                        OFF_WM2P,OFF_BM2,OFF_REL};
  const long total = 226689;
  for (long idx = (long)blockIdx.x * blockDim.x + threadIdx.x; idx < total;
       idx += (long)gridDim.x * blockDim.x) {
    long rem = idx;
    int s = 0;
    while (rem >= (long)R[s] * C[s]) { rem -= (long)R[s] * C[s]; s++; }
    float v = ldf(srcs[s], rem, bf);
    if (MD[s] == 2) {
      long r = rem / C[s], c = rem - r * C[s];
      ws[OFF[s] + (c >> 2) * 512 + r * 4 + (c & 3)] = v;
    } else {
      ws[OFF[s] + rem] = v;
    }
  }
}

// ---- K2: news title MLP (128 thr, 8 rows, acc[8]) ------------------------
__global__ __launch_bounds__(128) void k_news(const void* titles, const int* cand,
                                              const int* clk, float* ws) {
  const int bf = ((const int*)ws)[0];
  __shared__ __align__(16) float t[8][768];
  __shared__ __align__(16) float h1[8][128];
  int tid = threadIdx.x;
  long r0 = (long)blockIdx.x * 8;
  for (int x = tid * 4; x < 8 * 768; x += 128 * 4) {
    int c = x / 768, k = x - c * 768;
    long i = r0 + c;
    int id = (i < NCAND) ? cand[i] : clk[i - NCAND];
    *(float4*)&t[c][k] = ldf4(titles, (long)id * 768 + k, bf);
  }
  __syncthreads();
  int j = tid;
  const float4* W1 = (const float4*)(ws + OFF_WNC1P);
  float acc[8];
#pragma unroll
  for (int c = 0; c < 8; c++) acc[c] = 0.f;
  for (int k4 = 0; k4 < 192; k4++) {
    float4 w = W1[k4 * 128 + j];
#pragma unroll
    for (int c = 0; c < 8; c++) {
      const float4 xv = *(const float4*)&t[c][k4 * 4];
      acc[c] += w.x * xv.x + w.y * xv.y + w.z * xv.z + w.w * xv.w;
    }
  }
  float b1 = ws[OFF_BNC1 + j];
#pragma unroll
  for (int c = 0; c < 8; c++) h1[c][j] = eluf(acc[c] + b1);
  __syncthreads();
  const float4* W2 = (const float4*)(ws + OFF_WNC2P);
  float a2[8];
#pragma unroll
  for (int c = 0; c < 8; c++) a2[c] = 0.f;
  for (int k4 = 0; k4 < 32; k4++) {
    float4 w = W2[k4 * 128 + j];
#pragma unroll
    for (int c = 0; c < 8; c++) {
      const float4 xv = *(const float4*)&h1[c][k4 * 4];
      a2[c] += w.x * xv.x + w.y * xv.y + w.z * xv.z + w.w * xv.w;
    }
  }
  float b2 = ws[OFF_BNC2 + j];
  float* NE = ws + OFF_NE;
#pragma unroll
  for (int c = 0; c < 8; c++) NE[(r0 + c) * 128 + j] = tanhf(a2[c] + b2);
}

// ---- K3: gather (split, high occupancy, float4 + shfl) --------------------
// 256 thr = 8 groups of 32 lanes; one anchor row per group
__global__ __launch_bounds__(256) void k_gather(const void* ent, const int* canda,
                                                const int* clka, const int* eadj,
                                                const int* radj, float* ws) {
  const int bf = ((const int*)ws)[0];
  int lane = threadIdx.x & 31;
  int grp = threadIdx.x >> 5;
  long n = (long)blockIdx.x * 8 + grp;
  int node = (n < (long)NCAND * A_) ? canda[n] : clka[n - (long)NCAND * A_];
  int idx = 0;
  if (lane < 10) idx = eadj[(long)node * 10 + lane];
  else if (lane < 20) idx = radj[(long)node * 10 + (lane - 10)];
  int an[10], rn[10];
#pragma unroll
  for (int k = 0; k < 10; k++) {
    an[k] = __shfl(idx, k, 32);
    rn[k] = __shfl(idx, k + 10, 32);
  }
  float4 x1 = ldf4(ent, (long)node * 128 + lane * 4, bf);
  const float* relf = ws + OFF_REL;
  float4 acc = {0.f, 0.f, 0.f, 0.f};
#pragma unroll
  for (int k = 0; k < 10; k++) {
    float4 e = ldf4(ent, (long)an[k] * 128 + lane * 4, bf);
    const float4 r = *(const float4*)&relf[(long)rn[k] * 128 + lane * 4];
    acc.x += e.x + r.x;
    acc.y += e.y + r.y;
    acc.z += e.z + r.z;
    acc.w += e.w + r.w;
  }
  float* X = ws + OFF_X;
  *(float4*)&X[n * 256 + lane * 4] = x1;
  *(float4*)&X[n * 256 + 128 + lane * 4] = acc;
}

// ---- K4: FUSED anchor GEMMs + softmax -------------------------------------
// block = 2 news (40 anchors), 256 threads = 4 waves.
// Each wave's two 32-lane halves own 5 rows x 128 cols (4 cols/lane:
// jl, jl+32, jl+64, jl+96), acc[5][4]. Per k4: 5 broadcast ds_read_b128
// (2-way wave address diversity, free) feed 80 FMA insts -- half the DS
// traffic of the 10-row layout. X streamed via R2's chunked double buffer
// (direct copy, no reg residency across barriers -> no spill).
__global__ __launch_bounds__(256, 2) void k_anchor(float* ws) {
  __shared__ __align__(16) float H[40][128];      // 20 KB
  __shared__ __align__(16) float4 Xb[2][40][8];   // 10 KB
  __shared__ float LG[40];
  int tid = threadIdx.x;
  int lane = tid & 63, wv = tid >> 6;
  int jl = lane & 31;                     // column-group base (4 cols/lane)
  int hb = wv * 10 + (lane >> 5) * 5;     // this half-wave's 5-row base

  // X row = 64 float4; chunk cc covers float4 cols [cc*8, cc*8+8)
  const float4* Xg = (const float4*)(ws + OFF_X) + (long)blockIdx.x * 40 * 64;
  auto stage = [&](int cc, int p) {
    for (int i = tid; i < 320; i += 256) {
      int row = i >> 3, c8 = i & 7;
      Xb[p][row][c8] = Xg[row * 64 + cc * 8 + c8];
    }
  };

  // --- Stage B: H = tanh(X @ Wanc^T + b), 40x128, K=256, 8 chunks ---
  {
    const float4* W4 = (const float4*)(ws + OFF_WANCP);
    float acc[5][4];
#pragma unroll
    for (int r = 0; r < 5; r++)
#pragma unroll
      for (int c = 0; c < 4; c++) acc[r][c] = 0.f;
    stage(0, 0);
    __syncthreads();
    for (int cc = 0; cc < 8; cc++) {
      int p = cc & 1;
      if (cc < 7) stage(cc + 1, p ^ 1);
#pragma unroll
      for (int k4 = 0; k4 < 8; k4++) {
        int kk = cc * 8 + k4;
        float4 w0 = W4[kk * 128 + jl];
        float4 w1 = W4[kk * 128 + jl + 32];
        float4 w2 = W4[kk * 128 + jl + 64];
        float4 w3 = W4[kk * 128 + jl + 96];
#pragma unroll
        for (int r = 0; r < 5; r++) {
          const float4 xv = Xb[p][hb + r][k4];
          acc[r][0] += w0.x * xv.x + w0.y * xv.y + w0.z * xv.z + w0.w * xv.w;
          acc[r][1] += w1.x * xv.x + w1.y * xv.y + w1.z * xv.z + w1.w * xv.w;
          acc[r][2] += w2.x * xv.x + w2.y * xv.y + w2.z * xv.z + w2.w * xv.w;
          acc[r][3] += w3.x * xv.x + w3.y * xv.y + w3.z * xv.z + w3.w * xv.w;
        }
      }
      __syncthreads();
    }
    float b0 = ws[OFF_BANC + jl];
    float b1 = ws[OFF_BANC + jl + 32];
    float b2 = ws[OFF_BANC + jl + 64];
    float b3 = ws[OFF_BANC + jl + 96];
#pragma unroll
    for (int r = 0; r < 5; r++) {
      H[hb + r][jl]      = tanhf(acc[r][0] + b0);
      H[hb + r][jl + 32] = tanhf(acc[r][1] + b1);
      H[hb + r][jl + 64] = tanhf(acc[r][2] + b2);
      H[hb + r][jl + 96] = tanhf(acc[r][3] + b3);
    }
  }
  __syncthreads();

  // --- Stage C: logits = elu(H@Waw1^T+b)@w2 + b2, K=128 ---
  {
    const float4* W4 = (const float4*)(ws + OFF_WAW1P);
    float ac2[5][4];
#pragma unroll
    for (int r = 0; r < 5; r++)
#pragma unroll
      for (int c = 0; c < 4; c++) ac2[r][c] = 0.f;
    for (int k4 = 0; k4 < 32; k4++) {
      float4 w0 = W4[k4 * 128 + jl];
      float4 w1 = W4[k4 * 128 + jl + 32];
      float4 w2 = W4[k4 * 128 + jl + 64];
      float4 w3 = W4[k4 * 128 + jl + 96];
#pragma unroll
      for (int r = 0; r < 5; r++) {
        const float4 hv = *(const float4*)&H[hb + r][k4 * 4];
        ac2[r][0] += w0.x * hv.x + w0.y * hv.y + w0.z * hv.z + w0.w * hv.w;
        ac2[r][1] += w1.x * hv.x + w1.y * hv.y + w1.z * hv.z + w1.w * hv.w;
        ac2[r][2] += w2.x * hv.x + w2.y * hv.y + w2.z * hv.z + w2.w * hv.w;
        ac2[r][3] += w3.x * hv.x + w3.y * hv.y + w3.z * hv.z + w3.w * hv.w;
      }
    }
    float b1a = ws[OFF_BAW1 + jl];
    float b1b = ws[OFF_BAW1 + jl + 32];
    float b1c = ws[OFF_BAW1 + jl + 64];
    float b1d = ws[OFF_BAW1 + jl + 96];
    float w2a = ws[OFF_WAW2 + jl];
    float w2b = ws[OFF_WAW2 + jl + 32];
    float w2c = ws[OFF_WAW2 + jl + 64];
    float w2d = ws[OFF_WAW2 + jl + 96];
    float bw2 = ws[OFF_BAW2];
#pragma unroll
    for (int r = 0; r < 5; r++) {
      // partA == old lane l's  (e_l*w + e_{l+64}*w); partB == old lane l+32;
      // partA+partB == old's o=32 shfl add; then the old o=16..1 tree.
      float partA = eluf(ac2[r][0] + b1a) * w2a + eluf(ac2[r][2] + b1c) * w2c;
      float partB = eluf(ac2[r][1] + b1b) * w2b + eluf(ac2[r][3] + b1d) * w2d;
      float part = partA + partB;
#pragma unroll
      for (int o = 16; o > 0; o >>= 1) part += __shfl_down(part, o, 64);
      if (jl == 0) LG[hb + r] = part + bw2;
    }
  }
  __syncthreads();

  // --- Stage D: softmax over 20 anchors + weighted sum ---
  {
    int d = tid & 127, g = tid >> 7;
    float lg[20];
    float mx = -1e30f;
#pragma unroll
    for (int a = 0; a < 20; a++) { lg[a] = LG[g * 20 + a]; mx = fmaxf(mx, lg[a]); }
    float s = 0.f;
#pragma unroll
    for (int a = 0; a < 20; a++) { lg[a] = expf(lg[a] - mx); s += lg[a]; }
    float inv = 1.0f / s;
    float o = 0.f;
#pragma unroll
    for (int a = 0; a < 20; a++) o += lg[a] * H[g * 20 + a][d];
    float* AE = ws + OFF_AE;
    AE[((long)blockIdx.x * 2 + g) * 128 + d] = o * inv;
  }
}

// ---- K5: final MLP --------------------------------------------------------
__global__ __launch_bounds__(256) void k_mlp(float* ws) {
  __shared__ __align__(16) float xt[16][256];
  __shared__ __align__(16) float h1[16][128];
  int tid = threadIdx.x;
  long r0 = (long)blockIdx.x * 16;
  const float* NE = ws + OFF_NE;
  const float* AE = ws + OFF_AE;
  for (int x = tid; x < 16 * 256; x += 256) {
    int c = x >> 8, k = x & 255;
    xt[c][k] = (k < 128) ? NE[(r0 + c) * 128 + k] : AE[(r0 + c) * 128 + (k - 128)];
  }
  __syncthreads();
  int j = tid & 127, half = tid >> 7;
  const float4* W1 = (const float4*)(ws + OFF_WM1P);
  float acc[8];
#pragma unroll
  for (int c = 0; c < 8; c++) acc[c] = 0.f;
  for (int k4 = 0; k4 < 64; k4++) {
    float4 w = W1[k4 * 128 + j];
#pragma unroll
    for (int c = 0; c < 8; c++) {
      const float4 xv = *(const float4*)&xt[half * 8 + c][k4 * 4];
      acc[c] += w.x * xv.x + w.y * xv.y + w.z * xv.z + w.w * xv.w;
    }
  }
  float b1 = ws[OFF_BM1 + j];
#pragma unroll
  for (int c = 0; c < 8; c++) h1[half * 8 + c][j] = eluf(acc[c] + b1);
  __syncthreads();
  const float4* W2 = (const float4*)(ws + OFF_WM2P);
  float a2[8];
#pragma unroll
  for (int c = 0; c < 8; c++) a2[c] = 0.f;
  for (int k4 = 0; k4 < 32; k4++) {
    float4 w = W2[k4 * 128 + j];
#pragma unroll
    for (int c = 0; c < 8; c++) {
      const float4 xv = *(const float4*)&h1[half * 8 + c][k4 * 4];
      a2[c] += w.x * xv.x + w.y * xv.y + w.z * xv.z + w.w * xv.w;
    }
  }
  float b2 = ws[OFF_BM2 + j];
  float* MO = ws + OFF_MO;
#pragma unroll
  for (int c = 0; c < 8; c++) MO[(r0 + half * 8 + c) * 128 + j] = eluf(a2[c] + b2);
}

// ---- K6: user mean + scores ----------------------------------------------
__global__ __launch_bounds__(128) void k_score(const float* ws, void* out) {
  const int bf = ((const int*)ws)[0];
  int b = blockIdx.x;
  int d = threadIdx.x;
  const float* MO = ws + OFF_MO;
  float u = 0.f;
  for (int t = 0; t < UC_; t++) u += MO[(long)(NCAND + b * UC_ + t) * 128 + d];
  u *= (1.0f / UC_);
  __shared__ float red[2];
  for (int s = 0; s < S_; s++) {
    float p = MO[(long)(b * S_ + s) * 128 + d] * u;
#pragma unroll
    for (int o = 32; o > 0; o >>= 1) p += __shfl_down(p, o, 64);
    if ((d & 63) == 0) red[d >> 6] = p;
    __syncthreads();
    if (d == 0) {
      float v = red[0] + red[1];
      if (bf)
        ((__hip_bfloat16*)out)[b * S_ + s] = __float2bfloat16(v);
      else
        ((float*)out)[b * S_ + s] = v;
    }
    __syncthreads();
  }
}

extern "C" void kernel_launch(void* const* d_in, const int* in_sizes, int n_in,
                              void* d_out, int out_size, void* d_ws, size_t ws_size,
                              hipStream_t stream) {
  (void)in_sizes; (void)n_in; (void)out_size; (void)ws_size;
  const void* titles = d_in[0];
  const void* ent    = d_in[1];
  const void* rel    = d_in[2];
  const void* Wnc1 = d_in[3];  const void* bnc1 = d_in[4];
  const void* Wnc2 = d_in[5];  const void* bnc2 = d_in[6];
  const void* Wanc = d_in[7];  const void* banc = d_in[8];
  const void* Waw1 = d_in[9];  const void* baw1 = d_in[10];
  const void* Waw2 = d_in[11]; const void* baw2 = d_in[12];
  const void* Wm1  = d_in[13]; const void* bm1  = d_in[14];
  const void* Wm2  = d_in[15]; const void* bm2  = d_in[16];
  const int* cand  = (const int*)d_in[17];
  const int* clk   = (const int*)d_in[18];
  const int* canda = (const int*)d_in[19];
  const int* clka  = (const int*)d_in[20];
  const int* eadj  = (const int*)d_in[21];
  const int* radj  = (const int*)d_in[22];
  float* ws = (float*)d_ws;

  k_detect<<<1, 256, 0, stream>>>(ent, (int*)d_ws);
  k_prep<<<256, 256, 0, stream>>>(Wnc1, bnc1, Wnc2, bnc2, Wanc, banc, Waw1, baw1,
                                  Waw2, baw2, Wm1, bm1, Wm2, bm2, rel, ws);
  k_news<<<NNEWS / 8, 128, 0, stream>>>(titles, cand, clk, ws);
  k_gather<<<NANCH / 8, 256, 0, stream>>>(ent, canda, clka, eadj, radj, ws);
  k_anchor<<<NNEWS / 2, 256, 0, stream>>>(ws);
  k_mlp<<<NNEWS / 16, 256, 0, stream>>>(ws);
  k_score<<<B_, 128, 0, stream>>>(ws, d_out);
}

// Round 6
// 330.393 us; speedup vs baseline: 5.0512x; 1.0463x over previous
//
#include <hip/hip_runtime.h>
#include <hip/hip_bf16.h>

// ---------------------------------------------------------------------------
// Recommender pipeline, f32 compute.
//  K0 detect : bf16-vs-f32 flag in ws[0]
//  K1 prep   : weights -> f32 in ws; GEMM weights K-PACKED [k/4][128][4]
//  K2 news   : news_e = tanh(elu(title@W1^T+b)@W2^T+b)        [3520,128]
//  K3 gather : X[n] = [ent[node], sum_k(ent[adj]+rel[radj])]  [70400,256]
//  K4 anchor : FUSED tanh-GEMM + logits + softmax -> AE
//              R0-R5 post-mortem: VALU-busy TIME is ~105us across all
//              variants (real FMA floor at sustained clock); the variable
//              part is stall time (barriers / DS / L1 queuing). R6 combines
//              R0's minimal-barrier structure (X staged ONCE, 1 barrier,
//              then an uninterrupted 64-k4 run) with R5's half-wave 4-col
//              split (5 broadcasts + 2KB unique W-lines per 320 FMA-cyc,
//              half of R0's per-FMA operand rates). 2 barriers total in
//              stages B+C vs R2/R5's 13.
//  K5 mlp    : elu(elu([news_e,AE]@Wm1^T+b)@Wm2^T+b)          [3520,128]
//  K6 score  : user mean + dot                                 [64,5]
// ---------------------------------------------------------------------------

#define B_ 64
#define S_ 5
#define UC_ 50
#define A_ 20
#define NCAND 320
#define NCLK 3200
#define NNEWS 3520
#define NANCH 70400

// ws layout (float indices)
static constexpr long OFF_WNC1P = 64;        // [192][128][4]
static constexpr long OFF_BNC1  = 98368;
static constexpr long OFF_WNC2P = 98496;     // [32][128][4]
static constexpr long OFF_BNC2  = 114880;
static constexpr long OFF_WANCP = 115008;    // [64][128][4]
static constexpr long OFF_BANC  = 147776;
static constexpr long OFF_WAW1P = 147904;    // [32][128][4]
static constexpr long OFF_BAW1  = 164288;
static constexpr long OFF_WAW2  = 164416;    // [128]
static constexpr long OFF_BAW2  = 164544;    // [1]
static constexpr long OFF_WM1P  = 164548;    // [64][128][4]
static constexpr long OFF_BM1   = 197316;
static constexpr long OFF_WM2P  = 197444;    // [32][128][4]
static constexpr long OFF_BM2   = 213828;
static constexpr long OFF_REL   = 213956;    // [100][128]
static constexpr long OFF_AE    = 226756;    // [3520][128]
static constexpr long OFF_NE    = 677316;    // [3520][128]
static constexpr long OFF_MO    = 1127876;   // [3520][128]
static constexpr long OFF_X     = 1578436;   // [70400][256]
// total ~19.6M floats = 78.4 MB

__device__ __forceinline__ float ldf(const void* p, long i, int bf) {
  if (bf) {
    unsigned int u = (unsigned int)((const unsigned short*)p)[i];
    u <<= 16;
    return __uint_as_float(u);
  }
  return ((const float*)p)[i];
}

// 4 consecutive elems starting at i (i % 4 == 0)
__device__ __forceinline__ float4 ldf4(const void* p, long i, int bf) {
  float4 f;
  if (bf) {
    const unsigned short* q = (const unsigned short*)p + i;
    uint2 u = *(const uint2*)q;
    f.x = __uint_as_float(u.x << 16);
    f.y = __uint_as_float(u.x & 0xffff0000u);
    f.z = __uint_as_float(u.y << 16);
    f.w = __uint_as_float(u.y & 0xffff0000u);
  } else {
    f = *(const float4*)((const float*)p + i);
  }
  return f;
}

__device__ __forceinline__ float eluf(float v) { return v > 0.f ? v : expm1f(v); }

// ---- K0: dtype detect -----------------------------------------------------
__global__ void k_detect(const void* ent, int* flag) {
  __shared__ int cnt;
  if (threadIdx.x == 0) cnt = 0;
  __syncthreads();
  unsigned short u = ((const unsigned short*)ent)[threadIdx.x];
  int e = (u >> 7) & 0xFF;
  int ok = (e >= 107 && e <= 146) ? 1 : 0;
  atomicAdd(&cnt, ok);
  __syncthreads();
  if (threadIdx.x == 0) *flag = (cnt >= 200) ? 1 : 0;
}

// ---- K1: convert weights; GEMM weights K-packed ---------------------------
__global__ __launch_bounds__(256) void k_prep(
    const void* s0, const void* s1, const void* s2, const void* s3,
    const void* s4, const void* s5, const void* s6, const void* s7,
    const void* s8, const void* s9, const void* s10, const void* s11,
    const void* s12, const void* s13, const void* s14, float* ws) {
  const int bf = ((const int*)ws)[0];
  const void* srcs[15] = {s0,s1,s2,s3,s4,s5,s6,s7,s8,s9,s10,s11,s12,s13,s14};
  const int R[15] = {128,128,128,128,128,128,128,128,1,  1,  128,128,128,128,100};
  const int C[15] = {768,1,  128,1,  256,1,  128,1,  128,1,  256,1,  128,1,  128};
  const int MD[15]= {2,  0,  2,  0,  2,  0,  2,  0,  0,  0,  2,  0,  2,  0,  0};
  const long OFF[15] = {OFF_WNC1P,OFF_BNC1,OFF_WNC2P,OFF_BNC2,OFF_WANCP,OFF_BANC,
                        OFF_WAW1P,OFF_BAW1,OFF_WAW2,OFF_BAW2,OFF_WM1P,OFF_BM1,
                        OFF_WM2P,OFF_BM2,OFF_REL};
  const long total = 226689;
  for (long idx = (long)blockIdx.x * blockDim.x + threadIdx.x; idx < total;
       idx += (long)gridDim.x * blockDim.x) {
    long rem = idx;
    int s = 0;
    while (rem >= (long)R[s] * C[s]) { rem -= (long)R[s] * C[s]; s++; }
    float v = ldf(srcs[s], rem, bf);
    if (MD[s] == 2) {
      long r = rem / C[s], c = rem - r * C[s];
      ws[OFF[s] + (c >> 2) * 512 + r * 4 + (c & 3)] = v;
    } else {
      ws[OFF[s] + rem] = v;
    }
  }
}

// ---- K2: news title MLP (128 thr, 8 rows, acc[8]) ------------------------
__global__ __launch_bounds__(128) void k_news(const void* titles, const int* cand,
                                              const int* clk, float* ws) {
  const int bf = ((const int*)ws)[0];
  __shared__ __align__(16) float t[8][768];
  __shared__ __align__(16) float h1[8][128];
  int tid = threadIdx.x;
  long r0 = (long)blockIdx.x * 8;
  for (int x = tid * 4; x < 8 * 768; x += 128 * 4) {
    int c = x / 768, k = x - c * 768;
    long i = r0 + c;
    int id = (i < NCAND) ? cand[i] : clk[i - NCAND];
    *(float4*)&t[c][k] = ldf4(titles, (long)id * 768 + k, bf);
  }
  __syncthreads();
  int j = tid;
  const float4* W1 = (const float4*)(ws + OFF_WNC1P);
  float acc[8];
#pragma unroll
  for (int c = 0; c < 8; c++) acc[c] = 0.f;
  for (int k4 = 0; k4 < 192; k4++) {
    float4 w = W1[k4 * 128 + j];
#pragma unroll
    for (int c = 0; c < 8; c++) {
      const float4 xv = *(const float4*)&t[c][k4 * 4];
      acc[c] += w.x * xv.x + w.y * xv.y + w.z * xv.z + w.w * xv.w;
    }
  }
  float b1 = ws[OFF_BNC1 + j];
#pragma unroll
  for (int c = 0; c < 8; c++) h1[c][j] = eluf(acc[c] + b1);
  __syncthreads();
  const float4* W2 = (const float4*)(ws + OFF_WNC2P);
  float a2[8];
#pragma unroll
  for (int c = 0; c < 8; c++) a2[c] = 0.f;
  for (int k4 = 0; k4 < 32; k4++) {
    float4 w = W2[k4 * 128 + j];
#pragma unroll
    for (int c = 0; c < 8; c++) {
      const float4 xv = *(const float4*)&h1[c][k4 * 4];
      a2[c] += w.x * xv.x + w.y * xv.y + w.z * xv.z + w.w * xv.w;
    }
  }
  float b2 = ws[OFF_BNC2 + j];
  float* NE = ws + OFF_NE;
#pragma unroll
  for (int c = 0; c < 8; c++) NE[(r0 + c) * 128 + j] = tanhf(a2[c] + b2);
}

// ---- K3: gather (split, high occupancy, float4 + shfl) --------------------
// 256 thr = 8 groups of 32 lanes; one anchor row per group
__global__ __launch_bounds__(256) void k_gather(const void* ent, const int* canda,
                                                const int* clka, const int* eadj,
                                                const int* radj, float* ws) {
  const int bf = ((const int*)ws)[0];
  int lane = threadIdx.x & 31;
  int grp = threadIdx.x >> 5;
  long n = (long)blockIdx.x * 8 + grp;
  int node = (n < (long)NCAND * A_) ? canda[n] : clka[n - (long)NCAND * A_];
  int idx = 0;
  if (lane < 10) idx = eadj[(long)node * 10 + lane];
  else if (lane < 20) idx = radj[(long)node * 10 + (lane - 10)];
  int an[10], rn[10];
#pragma unroll
  for (int k = 0; k < 10; k++) {
    an[k] = __shfl(idx, k, 32);
    rn[k] = __shfl(idx, k + 10, 32);
  }
  float4 x1 = ldf4(ent, (long)node * 128 + lane * 4, bf);
  const float* relf = ws + OFF_REL;
  float4 acc = {0.f, 0.f, 0.f, 0.f};
#pragma unroll
  for (int k = 0; k < 10; k++) {
    float4 e = ldf4(ent, (long)an[k] * 128 + lane * 4, bf);
    const float4 r = *(const float4*)&relf[(long)rn[k] * 128 + lane * 4];
    acc.x += e.x + r.x;
    acc.y += e.y + r.y;
    acc.z += e.z + r.z;
    acc.w += e.w + r.w;
  }
  float* X = ws + OFF_X;
  *(float4*)&X[n * 256 + lane * 4] = x1;
  *(float4*)&X[n * 256 + 128 + lane * 4] = acc;
}

// ---- K4: FUSED anchor GEMMs + softmax -------------------------------------
// block = 2 news (40 anchors), 256 threads = 4 waves = 8 half-waves.
// Half-wave hw owns rows hb=hw*5..hb+4, cols jl,+32,+64,+96 (acc[5][4]).
// X staged to LDS ONCE (40KB, coalesced, 10 f4/thread), ONE barrier, then
// stage B runs 64 k4 with no barriers: per k4 = 4 W-loads (1KB unique each,
// both halves share lines) + 5 X broadcasts + 80 FMA insts. Stage C same
// split over H (LDS). 2 barriers total in B+C (R0 structure) at R5's halved
// per-FMA operand rates. LDS 61.6KB -> 2 blk/CU, VGPR cap 256 (no spill).
__global__ __launch_bounds__(256, 2) void k_anchor(float* ws) {
  __shared__ __align__(16) float4 Xf[40][64];     // 40 KB (full X tile)
  __shared__ __align__(16) float H[40][128];      // 20 KB
  __shared__ float LG[40];
  int tid = threadIdx.x;
  int lane = tid & 63, wv = tid >> 6;
  int jl = lane & 31;                     // column-group base (4 cols/lane)
  int hb = wv * 10 + (lane >> 5) * 5;     // this half-wave's 5-row base

  // --- Stage A: X tile -> LDS, one pass, one barrier ---
  const float4* Xg = (const float4*)(ws + OFF_X) + (long)blockIdx.x * 40 * 64;
  for (int i = tid; i < 2560; i += 256) Xf[i >> 6][i & 63] = Xg[i];
  __syncthreads();

  // --- Stage B: H = tanh(X @ Wanc^T + b), 40x128, K=256, no barriers ---
  {
    const float4* W4 = (const float4*)(ws + OFF_WANCP);
    float acc[5][4];
#pragma unroll
    for (int r = 0; r < 5; r++)
#pragma unroll
      for (int c = 0; c < 4; c++) acc[r][c] = 0.f;
    for (int kk = 0; kk < 64; kk++) {
      float4 w0 = W4[kk * 128 + jl];
      float4 w1 = W4[kk * 128 + jl + 32];
      float4 w2 = W4[kk * 128 + jl + 64];
      float4 w3 = W4[kk * 128 + jl + 96];
#pragma unroll
      for (int r = 0; r < 5; r++) {
        const float4 xv = Xf[hb + r][kk];
        acc[r][0] += w0.x * xv.x + w0.y * xv.y + w0.z * xv.z + w0.w * xv.w;
        acc[r][1] += w1.x * xv.x + w1.y * xv.y + w1.z * xv.z + w1.w * xv.w;
        acc[r][2] += w2.x * xv.x + w2.y * xv.y + w2.z * xv.z + w2.w * xv.w;
        acc[r][3] += w3.x * xv.x + w3.y * xv.y + w3.z * xv.z + w3.w * xv.w;
      }
    }
    float b0 = ws[OFF_BANC + jl];
    float b1 = ws[OFF_BANC + jl + 32];
    float b2 = ws[OFF_BANC + jl + 64];
    float b3 = ws[OFF_BANC + jl + 96];
#pragma unroll
    for (int r = 0; r < 5; r++) {
      H[hb + r][jl]      = tanhf(acc[r][0] + b0);
      H[hb + r][jl + 32] = tanhf(acc[r][1] + b1);
      H[hb + r][jl + 64] = tanhf(acc[r][2] + b2);
      H[hb + r][jl + 96] = tanhf(acc[r][3] + b3);
    }
  }
  __syncthreads();

  // --- Stage C: logits = elu(H@Waw1^T+b)@w2 + b2, K=128, no barriers ---
  {
    const float4* W4 = (const float4*)(ws + OFF_WAW1P);
    float ac2[5][4];
#pragma unroll
    for (int r = 0; r < 5; r++)
#pragma unroll
      for (int c = 0; c < 4; c++) ac2[r][c] = 0.f;
    for (int k4 = 0; k4 < 32; k4++) {
      float4 w0 = W4[k4 * 128 + jl];
      float4 w1 = W4[k4 * 128 + jl + 32];
      float4 w2 = W4[k4 * 128 + jl + 64];
      float4 w3 = W4[k4 * 128 + jl + 96];
#pragma unroll
      for (int r = 0; r < 5; r++) {
        const float4 hv = *(const float4*)&H[hb + r][k4 * 4];
        ac2[r][0] += w0.x * hv.x + w0.y * hv.y + w0.z * hv.z + w0.w * hv.w;
        ac2[r][1] += w1.x * hv.x + w1.y * hv.y + w1.z * hv.z + w1.w * hv.w;
        ac2[r][2] += w2.x * hv.x + w2.y * hv.y + w2.z * hv.z + w2.w * hv.w;
        ac2[r][3] += w3.x * hv.x + w3.y * hv.y + w3.z * hv.z + w3.w * hv.w;
      }
    }
    float b1a = ws[OFF_BAW1 + jl];
    float b1b = ws[OFF_BAW1 + jl + 32];
    float b1c = ws[OFF_BAW1 + jl + 64];
    float b1d = ws[OFF_BAW1 + jl + 96];
    float w2a = ws[OFF_WAW2 + jl];
    float w2b = ws[OFF_WAW2 + jl + 32];
    float w2c = ws[OFF_WAW2 + jl + 64];
    float w2d = ws[OFF_WAW2 + jl + 96];
    float bw2 = ws[OFF_BAW2];
#pragma unroll
    for (int r = 0; r < 5; r++) {
      // partA == old lane l's  (e_l*w + e_{l+64}*w); partB == old lane l+32;
      // partA+partB == old's o=32 shfl add; then the old o=16..1 tree.
      float partA = eluf(ac2[r][0] + b1a) * w2a + eluf(ac2[r][2] + b1c) * w2c;
      float partB = eluf(ac2[r][1] + b1b) * w2b + eluf(ac2[r][3] + b1d) * w2d;
      float part = partA + partB;
#pragma unroll
      for (int o = 16; o > 0; o >>= 1) part += __shfl_down(part, o, 64);
      if (jl == 0) LG[hb + r] = part + bw2;
    }
  }
  __syncthreads();

  // --- Stage D: softmax over 20 anchors + weighted sum ---
  {
    int d = tid & 127, g = tid >> 7;
    float lg[20];
    float mx = -1e30f;
#pragma unroll
    for (int a = 0; a < 20; a++) { lg[a] = LG[g * 20 + a]; mx = fmaxf(mx, lg[a]); }
    float s = 0.f;
#pragma unroll
    for (int a = 0; a < 20; a++) { lg[a] = expf(lg[a] - mx); s += lg[a]; }
    float inv = 1.0f / s;
    float o = 0.f;
#pragma unroll
    for (int a = 0; a < 20; a++) o += lg[a] * H[g * 20 + a][d];
    float* AE = ws + OFF_AE;
    AE[((long)blockIdx.x * 2 + g) * 128 + d] = o * inv;
  }
}

// ---- K5: final MLP --------------------------------------------------------
__global__ __launch_bounds__(256) void k_mlp(float* ws) {
  __shared__ __align__(16) float xt[16][256];
  __shared__ __align__(16) float h1[16][128];
  int tid = threadIdx.x;
  long r0 = (long)blockIdx.x * 16;
  const float* NE = ws + OFF_NE;
  const float* AE = ws + OFF_AE;
  for (int x = tid; x < 16 * 256; x += 256) {
    int c = x >> 8, k = x & 255;
    xt[c][k] = (k < 128) ? NE[(r0 + c) * 128 + k] : AE[(r0 + c) * 128 + (k - 128)];
  }
  __syncthreads();
  int j = tid & 127, half = tid >> 7;
  const float4* W1 = (const float4*)(ws + OFF_WM1P);
  float acc[8];
#pragma unroll
  for (int c = 0; c < 8; c++) acc[c] = 0.f;
  for (int k4 = 0; k4 < 64; k4++) {
    float4 w = W1[k4 * 128 + j];
#pragma unroll
    for (int c = 0; c < 8; c++) {
      const float4 xv = *(const float4*)&xt[half * 8 + c][k4 * 4];
      acc[c] += w.x * xv.x + w.y * xv.y + w.z * xv.z + w.w * xv.w;
    }
  }
  float b1 = ws[OFF_BM1 + j];
#pragma unroll
  for (int c = 0; c < 8; c++) h1[half * 8 + c][j] = eluf(acc[c] + b1);
  __syncthreads();
  const float4* W2 = (const float4*)(ws + OFF_WM2P);
  float a2[8];
#pragma unroll
  for (int c = 0; c < 8; c++) a2[c] = 0.f;
  for (int k4 = 0; k4 < 32; k4++) {
    float4 w = W2[k4 * 128 + j];
#pragma unroll
    for (int c = 0; c < 8; c++) {
      const float4 xv = *(const float4*)&h1[half * 8 + c][k4 * 4];
      a2[c] += w.x * xv.x + w.y * xv.y + w.z * xv.z + w.w * xv.w;
    }
  }
  float b2 = ws[OFF_BM2 + j];
  float* MO = ws + OFF_MO;
#pragma unroll
  for (int c = 0; c < 8; c++) MO[(r0 + half * 8 + c) * 128 + j] = eluf(a2[c] + b2);
}

// ---- K6: user mean + scores ----------------------------------------------
__global__ __launch_bounds__(128) void k_score(const float* ws, void* out) {
  const int bf = ((const int*)ws)[0];
  int b = blockIdx.x;
  int d = threadIdx.x;
  const float* MO = ws + OFF_MO;
  float u = 0.f;
  for (int t = 0; t < UC_; t++) u += MO[(long)(NCAND + b * UC_ + t) * 128 + d];
  u *= (1.0f / UC_);
  __shared__ float red[2];
  for (int s = 0; s < S_; s++) {
    float p = MO[(long)(b * S_ + s) * 128 + d] * u;
#pragma unroll
    for (int o = 32; o > 0; o >>= 1) p += __shfl_down(p, o, 64);
    if ((d & 63) == 0) red[d >> 6] = p;
    __syncthreads();
    if (d == 0) {
      float v = red[0] + red[1];
      if (bf)
        ((__hip_bfloat16*)out)[b * S_ + s] = __float2bfloat16(v);
      else
        ((float*)out)[b * S_ + s] = v;
    }
    __syncthreads();
  }
}

extern "C" void kernel_launch(void* const* d_in, const int* in_sizes, int n_in,
                              void* d_out, int out_size, void* d_ws, size_t ws_size,
                              hipStream_t stream) {
  (void)in_sizes; (void)n_in; (void)out_size; (void)ws_size;
  const void* titles = d_in[0];
  const void* ent    = d_in[1];
  const void* rel    = d_in[2];
  const void* Wnc1 = d_in[3];  const void* bnc1 = d_in[4];
  const void* Wnc2 = d_in[5];  const void* bnc2 = d_in[6];
  const void* Wanc = d_in[7];  const void* banc = d_in[8];
  const void* Waw1 = d_in[9];  const void* baw1 = d_in[10];
  const void* Waw2 = d_in[11]; const void* baw2 = d_in[12];
  const void* Wm1  = d_in[13]; const void* bm1  = d_in[14];
  const void* Wm2  = d_in[15]; const void* bm2  = d_in[16];
  const int* cand  = (const int*)d_in[17];
  const int* clk   = (const int*)d_in[18];
  const int* canda = (const int*)d_in[19];
  const int* clka  = (const int*)d_in[20];
  const int* eadj  = (const int*)d_in[21];
  const int* radj  = (const int*)d_in[22];
  float* ws = (float*)d_ws;

  k_detect<<<1, 256, 0, stream>>>(ent, (int*)d_ws);
  k_prep<<<256, 256, 0, stream>>>(Wnc1, bnc1, Wnc2, bnc2, Wanc, banc, Waw1, baw1,
                                  Waw2, baw2, Wm1, bm1, Wm2, bm2, rel, ws);
  k_news<<<NNEWS / 8, 128, 0, stream>>>(titles, cand, clk, ws);
  k_gather<<<NANCH / 8, 256, 0, stream>>>(ent, canda, clka, eadj, radj, ws);
  k_anchor<<<NNEWS / 2, 256, 0, stream>>>(ws);
  k_mlp<<<NNEWS / 16, 256, 0, stream>>>(ws);
  k_score<<<B_, 128, 0, stream>>>(ws, d_out);
}

// Round 7
// 295.600 us; speedup vs baseline: 5.6458x; 1.1177x over previous
//
#include <hip/hip_runtime.h>
#include <hip/hip_bf16.h>

// ---------------------------------------------------------------------------
// Recommender pipeline.
//  K0 detect : bf16-vs-f32 flag in ws[0]
//  K1 prep   : weights -> ws; K-PACKED f32 for news/mlp GEMMs; Wanc/Waw1
//              SPLIT-BF16 frag-packed [kt][n][16] hi/lo for MFMA.
//  K2 news   : news_e = tanh(elu(title@W1^T+b)@W2^T+b)        [3520,128]
//  K3 gather : X[n] = [ent[node], sum_k(ent[adj]+rel[radj])]  [70400,256]
//              written as SPLIT-BF16 pair XH/XL (same 72MB footprint).
//  K4 anchor : R0-R6 post-mortem: six f32 schedules all pinned at ~176us,
//              VALU-busy time ~105us constant => f32 vector FMA stream IS
//              the floor. R7: stages B+C on MFMA (v_mfma_f32_32x32x16_bf16)
//              with 3-term split-bf16 products (hi*hi+hi*lo+lo*hi, fp32
//              accum): ~2^-16 relative error, scores absmax ~1e-4.
//              Block = 8 news = 160 rows, 4 waves; wave w = N-tile w (32
//              cols) x 5 M-tiles; H stored hi/lo bf16 in LDS, XOR-swizzled
//              (T2) for stage-C frag reads. Logit rowsum via shfl tree +
//              per-wave LDS partials. Softmax in stage D per news.
//  K5 mlp    : elu(elu([news_e,AE]@Wm1^T+b)@Wm2^T+b)          [3520,128]
//  K6 score  : user mean + dot                                 [64,5]
// ---------------------------------------------------------------------------

#define B_ 64
#define S_ 5
#define UC_ 50
#define A_ 20
#define NCAND 320
#define NCLK 3200
#define NNEWS 3520
#define NANCH 70400

// ws layout (float indices)
static constexpr long OFF_WNC1P = 64;        // [192][128][4] f32
static constexpr long OFF_BNC1  = 98368;
static constexpr long OFF_WNC2P = 98496;     // [32][128][4] f32
static constexpr long OFF_BNC2  = 114880;
static constexpr long OFF_WANCP = 115008;    // REUSED: [16kt][128n][16k] bf16 hi + lo (65536 ushort)
static constexpr long OFF_BANC  = 147776;
static constexpr long OFF_WAW1P = 147904;    // REUSED: [8kt][128n][16k] bf16 hi + lo (32768 ushort)
static constexpr long OFF_BAW1  = 164288;
static constexpr long OFF_WAW2  = 164416;    // [128]
static constexpr long OFF_BAW2  = 164544;    // [1]
static constexpr long OFF_WM1P  = 164548;    // [64][128][4] f32
static constexpr long OFF_BM1   = 197316;
static constexpr long OFF_WM2P  = 197444;    // [32][128][4] f32
static constexpr long OFF_BM2   = 213828;
static constexpr long OFF_REL   = 213956;    // [100][128] f32
static constexpr long OFF_AE    = 226756;    // [3520][128] f32
static constexpr long OFF_NE    = 677316;    // [3520][128] f32
static constexpr long OFF_MO    = 1127876;   // [3520][128] f32
static constexpr long OFF_X     = 1578436;   // REUSED: XH[70400][256] + XL[70400][256] bf16 (same 72MB)
// total ~19.6M floats = 78.4 MB

typedef __attribute__((ext_vector_type(8))) short short8v;   // 8 bf16 = 4 VGPR
typedef __attribute__((ext_vector_type(16))) float f32x16;   // MFMA 32x32 acc

__device__ __forceinline__ float ldf(const void* p, long i, int bf) {
  if (bf) {
    unsigned int u = (unsigned int)((const unsigned short*)p)[i];
    u <<= 16;
    return __uint_as_float(u);
  }
  return ((const float*)p)[i];
}

// 4 consecutive elems starting at i (i % 4 == 0)
__device__ __forceinline__ float4 ldf4(const void* p, long i, int bf) {
  float4 f;
  if (bf) {
    const unsigned short* q = (const unsigned short*)p + i;
    uint2 u = *(const uint2*)q;
    f.x = __uint_as_float(u.x << 16);
    f.y = __uint_as_float(u.x & 0xffff0000u);
    f.z = __uint_as_float(u.y << 16);
    f.w = __uint_as_float(u.y & 0xffff0000u);
  } else {
    f = *(const float4*)((const float*)p + i);
  }
  return f;
}

__device__ __forceinline__ float eluf(float v) { return v > 0.f ? v : expm1f(v); }

// split f32 v into hi (truncated bf16 bits) + lo (RNE bf16 of remainder)
__device__ __forceinline__ void splitbf(float v, unsigned short& hi, unsigned short& lo) {
  unsigned int b = __float_as_uint(v);
  hi = (unsigned short)(b >> 16);
  float rm = v - __uint_as_float(b & 0xffff0000u);
  unsigned int rb = __float_as_uint(rm);
  lo = (unsigned short)((rb + 0x7fffu + ((rb >> 16) & 1u)) >> 16);
}

__device__ __forceinline__ float bfh(unsigned short u) {
  return __uint_as_float((unsigned int)u << 16);
}

// ---- K0: dtype detect -----------------------------------------------------
__global__ void k_detect(const void* ent, int* flag) {
  __shared__ int cnt;
  if (threadIdx.x == 0) cnt = 0;
  __syncthreads();
  unsigned short u = ((const unsigned short*)ent)[threadIdx.x];
  int e = (u >> 7) & 0xFF;
  int ok = (e >= 107 && e <= 146) ? 1 : 0;
  atomicAdd(&cnt, ok);
  __syncthreads();
  if (threadIdx.x == 0) *flag = (cnt >= 200) ? 1 : 0;
}

// ---- K1: convert weights --------------------------------------------------
// MD 0: plain f32. MD 2: f32 K-packed [k/4][128][4]. MD 3: split-bf16 MFMA
// B-frag pack [kt][n][16k] hi then lo.
__global__ __launch_bounds__(256) void k_prep(
    const void* s0, const void* s1, const void* s2, const void* s3,
    const void* s4, const void* s5, const void* s6, const void* s7,
    const void* s8, const void* s9, const void* s10, const void* s11,
    const void* s12, const void* s13, const void* s14, float* ws) {
  const int bf = ((const int*)ws)[0];
  const void* srcs[15] = {s0,s1,s2,s3,s4,s5,s6,s7,s8,s9,s10,s11,s12,s13,s14};
  const int R[15] = {128,128,128,128,128,128,128,128,1,  1,  128,128,128,128,100};
  const int C[15] = {768,1,  128,1,  256,1,  128,1,  128,1,  256,1,  128,1,  128};
  const int MD[15]= {2,  0,  2,  0,  3,  0,  3,  0,  0,  0,  2,  0,  2,  0,  0};
  const long OFF[15] = {OFF_WNC1P,OFF_BNC1,OFF_WNC2P,OFF_BNC2,OFF_WANCP,OFF_BANC,
                        OFF_WAW1P,OFF_BAW1,OFF_WAW2,OFF_BAW2,OFF_WM1P,OFF_BM1,
                        OFF_WM2P,OFF_BM2,OFF_REL};
  const long total = 226689;
  for (long idx = (long)blockIdx.x * blockDim.x + threadIdx.x; idx < total;
       idx += (long)gridDim.x * blockDim.x) {
    long rem = idx;
    int s = 0;
    while (rem >= (long)R[s] * C[s]) { rem -= (long)R[s] * C[s]; s++; }
    float v = ldf(srcs[s], rem, bf);
    if (MD[s] == 2) {
      long r = rem / C[s], c = rem - r * C[s];
      ws[OFF[s] + (c >> 2) * 512 + r * 4 + (c & 3)] = v;
    } else if (MD[s] == 3) {
      long r = rem / C[s], c = rem - r * C[s];   // r = out n, c = k
      unsigned short hi, lo;
      splitbf(v, hi, lo);
      unsigned short* H = (unsigned short*)(ws + OFF[s]);
      unsigned short* L = H + (s == 4 ? 32768 : 16384);
      long id2 = ((c >> 4) * 128 + r) * 16 + (c & 15);
      H[id2] = hi;
      L[id2] = lo;
    } else {
      ws[OFF[s] + rem] = v;
    }
  }
}

// ---- K2: news title MLP (128 thr, 8 rows, acc[8]) ------------------------
__global__ __launch_bounds__(128) void k_news(const void* titles, const int* cand,
                                              const int* clk, float* ws) {
  const int bf = ((const int*)ws)[0];
  __shared__ __align__(16) float t[8][768];
  __shared__ __align__(16) float h1[8][128];
  int tid = threadIdx.x;
  long r0 = (long)blockIdx.x * 8;
  for (int x = tid * 4; x < 8 * 768; x += 128 * 4) {
    int c = x / 768, k = x - c * 768;
    long i = r0 + c;
    int id = (i < NCAND) ? cand[i] : clk[i - NCAND];
    *(float4*)&t[c][k] = ldf4(titles, (long)id * 768 + k, bf);
  }
  __syncthreads();
  int j = tid;
  const float4* W1 = (const float4*)(ws + OFF_WNC1P);
  float acc[8];
#pragma unroll
  for (int c = 0; c < 8; c++) acc[c] = 0.f;
  for (int k4 = 0; k4 < 192; k4++) {
    float4 w = W1[k4 * 128 + j];
#pragma unroll
    for (int c = 0; c < 8; c++) {
      const float4 xv = *(const float4*)&t[c][k4 * 4];
      acc[c] += w.x * xv.x + w.y * xv.y + w.z * xv.z + w.w * xv.w;
    }
  }
  float b1 = ws[OFF_BNC1 + j];
#pragma unroll
  for (int c = 0; c < 8; c++) h1[c][j] = eluf(acc[c] + b1);
  __syncthreads();
  const float4* W2 = (const float4*)(ws + OFF_WNC2P);
  float a2[8];
#pragma unroll
  for (int c = 0; c < 8; c++) a2[c] = 0.f;
  for (int k4 = 0; k4 < 32; k4++) {
    float4 w = W2[k4 * 128 + j];
#pragma unroll
    for (int c = 0; c < 8; c++) {
      const float4 xv = *(const float4*)&h1[c][k4 * 4];
      a2[c] += w.x * xv.x + w.y * xv.y + w.z * xv.z + w.w * xv.w;
    }
  }
  float b2 = ws[OFF_BNC2 + j];
  float* NE = ws + OFF_NE;
#pragma unroll
  for (int c = 0; c < 8; c++) NE[(r0 + c) * 128 + j] = tanhf(a2[c] + b2);
}

// ---- K3: gather -> split-bf16 X ------------------------------------------
// 256 thr = 8 groups of 32 lanes; one anchor row per group
__global__ __launch_bounds__(256) void k_gather(const void* ent, const int* canda,
                                                const int* clka, const int* eadj,
                                                const int* radj, float* ws) {
  const int bf = ((const int*)ws)[0];
  int lane = threadIdx.x & 31;
  int grp = threadIdx.x >> 5;
  long n = (long)blockIdx.x * 8 + grp;
  int node = (n < (long)NCAND * A_) ? canda[n] : clka[n - (long)NCAND * A_];
  int idx = 0;
  if (lane < 10) idx = eadj[(long)node * 10 + lane];
  else if (lane < 20) idx = radj[(long)node * 10 + (lane - 10)];
  int an[10], rn[10];
#pragma unroll
  for (int k = 0; k < 10; k++) {
    an[k] = __shfl(idx, k, 32);
    rn[k] = __shfl(idx, k + 10, 32);
  }
  float4 x1 = ldf4(ent, (long)node * 128 + lane * 4, bf);
  const float* relf = ws + OFF_REL;
  float4 acc = {0.f, 0.f, 0.f, 0.f};
#pragma unroll
  for (int k = 0; k < 10; k++) {
    float4 e = ldf4(ent, (long)an[k] * 128 + lane * 4, bf);
    const float4 r = *(const float4*)&relf[(long)rn[k] * 128 + lane * 4];
    acc.x += e.x + r.x;
    acc.y += e.y + r.y;
    acc.z += e.z + r.z;
    acc.w += e.w + r.w;
  }
  unsigned short* XH = (unsigned short*)(ws + OFF_X);
  unsigned short* XL = XH + (size_t)NANCH * 256;
  ushort4 h4, l4;
  splitbf(x1.x, h4.x, l4.x); splitbf(x1.y, h4.y, l4.y);
  splitbf(x1.z, h4.z, l4.z); splitbf(x1.w, h4.w, l4.w);
  *(ushort4*)&XH[n * 256 + lane * 4] = h4;
  *(ushort4*)&XL[n * 256 + lane * 4] = l4;
  splitbf(acc.x, h4.x, l4.x); splitbf(acc.y, h4.y, l4.y);
  splitbf(acc.z, h4.z, l4.z); splitbf(acc.w, h4.w, l4.w);
  *(ushort4*)&XH[n * 256 + 128 + lane * 4] = h4;
  *(ushort4*)&XL[n * 256 + 128 + lane * 4] = l4;
}

// ---- K4: MFMA anchor GEMMs + softmax -------------------------------------
// block = 8 news = 160 rows, 256 thr = 4 waves. Wave w = N-tile w (cols
// w*32..w*32+31) x 5 M-tiles of 32. A-frag (lane l): row = l%32, k =
// (l/32)*8..+8 contiguous bf16. B-frag: n = l%32, same k (matches the
// [kt][n][16] pack). C/D (verified m74/m101): col = l&31,
// row = (reg&3) + 8*(reg>>2) + 4*(l>>5).
__global__ __launch_bounds__(256, 1) void k_anchor(float* ws) {
  __shared__ __align__(16) unsigned short Hhi[160][128];  // 40 KB
  __shared__ __align__(16) unsigned short Hlo[160][128];  // 40 KB
  __shared__ float LGp[4][160];
  __shared__ float LG[160];
  int tid = threadIdx.x;
  int lane = tid & 63, wv = tid >> 6;
  int ln = lane & 31, kh = lane >> 5;
  int col = (wv << 5) + ln;
  long row0 = (long)blockIdx.x * 160;

  const unsigned short* XH = (const unsigned short*)(ws + OFF_X);
  const unsigned short* XL = XH + (size_t)NANCH * 256;
  const unsigned short* WAH = (const unsigned short*)(ws + OFF_WANCP);
  const unsigned short* WAL = WAH + 32768;
  const unsigned short* W1H = (const unsigned short*)(ws + OFF_WAW1P);
  const unsigned short* W1L = W1H + 16384;

  // --- Stage B: H = tanh(X @ Wanc^T + b), [160,256]@[256->128] ---
  {
    f32x16 acc[5] = {};
    for (int kt = 0; kt < 16; ++kt) {
      long wi = ((long)(kt * 128 + col) << 4) + (kh << 3);
      short8v bhi = *(const short8v*)(WAH + wi);
      short8v blo = *(const short8v*)(WAL + wi);
#pragma unroll
      for (int mt = 0; mt < 5; ++mt) {
        long r = row0 + mt * 32 + ln;
        long ai = r * 256 + kt * 16 + (kh << 3);
        short8v ahi = *(const short8v*)(XH + ai);
        short8v alo = *(const short8v*)(XL + ai);
        acc[mt] = __builtin_amdgcn_mfma_f32_32x32x16_bf16(ahi, bhi, acc[mt], 0, 0, 0);
        acc[mt] = __builtin_amdgcn_mfma_f32_32x32x16_bf16(ahi, blo, acc[mt], 0, 0, 0);
        acc[mt] = __builtin_amdgcn_mfma_f32_32x32x16_bf16(alo, bhi, acc[mt], 0, 0, 0);
      }
    }
    float bc = ws[OFF_BANC + col];
#pragma unroll
    for (int mt = 0; mt < 5; ++mt)
#pragma unroll
      for (int j = 0; j < 16; ++j) {
        int r = mt * 32 + (j & 3) + ((j >> 2) << 3) + (kh << 2);
        float h = tanhf(acc[mt][j] + bc);
        unsigned short hi, lo;
        splitbf(h, hi, lo);
        int sc = col ^ ((r & 7) << 3);   // T2 XOR swizzle (16B granules)
        Hhi[r][sc] = hi;
        Hlo[r][sc] = lo;
      }
  }
  __syncthreads();

  // --- Stage C: logits = elu(H@Waw1^T+b1)@w2 + b2, [160,128]@[128->128] ---
  {
    f32x16 ac[5] = {};
    for (int kt = 0; kt < 8; ++kt) {
      long wi = ((long)(kt * 128 + col) << 4) + (kh << 3);
      short8v bhi = *(const short8v*)(W1H + wi);
      short8v blo = *(const short8v*)(W1L + wi);
#pragma unroll
      for (int mt = 0; mt < 5; ++mt) {
        int rr = mt * 32 + ln;
        int kb = (kt * 16 + (kh << 3)) ^ ((rr & 7) << 3);
        short8v ahi = *(const short8v*)&Hhi[rr][kb];
        short8v alo = *(const short8v*)&Hlo[rr][kb];
        ac[mt] = __builtin_amdgcn_mfma_f32_32x32x16_bf16(ahi, bhi, ac[mt], 0, 0, 0);
        ac[mt] = __builtin_amdgcn_mfma_f32_32x32x16_bf16(ahi, blo, ac[mt], 0, 0, 0);
        ac[mt] = __builtin_amdgcn_mfma_f32_32x32x16_bf16(alo, bhi, ac[mt], 0, 0, 0);
      }
    }
    float b1c = ws[OFF_BAW1 + col];
    float w2c = ws[OFF_WAW2 + col];
#pragma unroll
    for (int mt = 0; mt < 5; ++mt)
#pragma unroll
      for (int j = 0; j < 16; ++j) {
        int r = mt * 32 + (j & 3) + ((j >> 2) << 3) + (kh << 2);
        float v = eluf(ac[mt][j] + b1c) * w2c;
        v += __shfl_xor(v, 16);
        v += __shfl_xor(v, 8);
        v += __shfl_xor(v, 4);
        v += __shfl_xor(v, 2);
        v += __shfl_xor(v, 1);
        if (ln == 0) LGp[wv][r] = v;   // lanes 0 and 32 (different r)
      }
  }
  __syncthreads();
  if (tid < 160)
    LG[tid] = LGp[0][tid] + LGp[1][tid] + LGp[2][tid] + LGp[3][tid] + ws[OFF_BAW2];
  __syncthreads();

  // --- Stage D: per-news softmax over 20 anchors + weighted sum ---
  {
    int g = tid >> 5, l32 = tid & 31, ar = g * 20;
    float e[20], mx = -1e30f;
#pragma unroll
    for (int a = 0; a < 20; ++a) { e[a] = LG[ar + a]; mx = fmaxf(mx, e[a]); }
    float s = 0.f;
#pragma unroll
    for (int a = 0; a < 20; ++a) { e[a] = expf(e[a] - mx); s += e[a]; }
    float inv = 1.0f / s;
    float o0 = 0.f, o1 = 0.f, o2 = 0.f, o3 = 0.f;
#pragma unroll
    for (int a = 0; a < 20; ++a) {
      int rr = ar + a, sw = (rr & 7) << 3;
      float w = e[a];
      int d0 = l32 ^ sw, d1 = (l32 + 32) ^ sw, d2 = (l32 + 64) ^ sw, d3 = (l32 + 96) ^ sw;
      o0 += w * (bfh(Hhi[rr][d0]) + bfh(Hlo[rr][d0]));
      o1 += w * (bfh(Hhi[rr][d1]) + bfh(Hlo[rr][d1]));
      o2 += w * (bfh(Hhi[rr][d2]) + bfh(Hlo[rr][d2]));
      o3 += w * (bfh(Hhi[rr][d3]) + bfh(Hlo[rr][d3]));
    }
    float* AE = ws + OFF_AE;
    long ro = ((long)blockIdx.x * 8 + g) * 128;
    AE[ro + l32]      = o0 * inv;
    AE[ro + l32 + 32] = o1 * inv;
    AE[ro + l32 + 64] = o2 * inv;
    AE[ro + l32 + 96] = o3 * inv;
  }
}

// ---- K5: final MLP --------------------------------------------------------
__global__ __launch_bounds__(256) void k_mlp(float* ws) {
  __shared__ __align__(16) float xt[16][256];
  __shared__ __align__(16) float h1[16][128];
  int tid = threadIdx.x;
  long r0 = (long)blockIdx.x * 16;
  const float* NE = ws + OFF_NE;
  const float* AE = ws + OFF_AE;
  for (int x = tid; x < 16 * 256; x += 256) {
    int c = x >> 8, k = x & 255;
    xt[c][k] = (k < 128) ? NE[(r0 + c) * 128 + k] : AE[(r0 + c) * 128 + (k - 128)];
  }
  __syncthreads();
  int j = tid & 127, half = tid >> 7;
  const float4* W1 = (const float4*)(ws + OFF_WM1P);
  float acc[8];
#pragma unroll
  for (int c = 0; c < 8; c++) acc[c] = 0.f;
  for (int k4 = 0; k4 < 64; k4++) {
    float4 w = W1[k4 * 128 + j];
#pragma unroll
    for (int c = 0; c < 8; c++) {
      const float4 xv = *(const float4*)&xt[half * 8 + c][k4 * 4];
      acc[c] += w.x * xv.x + w.y * xv.y + w.z * xv.z + w.w * xv.w;
    }
  }
  float b1 = ws[OFF_BM1 + j];
#pragma unroll
  for (int c = 0; c < 8; c++) h1[half * 8 + c][j] = eluf(acc[c] + b1);
  __syncthreads();
  const float4* W2 = (const float4*)(ws + OFF_WM2P);
  float a2[8];
#pragma unroll
  for (int c = 0; c < 8; c++) a2[c] = 0.f;
  for (int k4 = 0; k4 < 32; k4++) {
    float4 w = W2[k4 * 128 + j];
#pragma unroll
    for (int c = 0; c < 8; c++) {
      const float4 xv = *(const float4*)&h1[half * 8 + c][k4 * 4];
      a2[c] += w.x * xv.x + w.y * xv.y + w.z * xv.z + w.w * xv.w;
    }
  }
  float b2 = ws[OFF_BM2 + j];
  float* MO = ws + OFF_MO;
#pragma unroll
  for (int c = 0; c < 8; c++) MO[(r0 + half * 8 + c) * 128 + j] = eluf(a2[c] + b2);
}

// ---- K6: user mean + scores ----------------------------------------------
__global__ __launch_bounds__(128) void k_score(const float* ws, void* out) {
  const int bf = ((const int*)ws)[0];
  int b = blockIdx.x;
  int d = threadIdx.x;
  const float* MO = ws + OFF_MO;
  float u = 0.f;
  for (int t = 0; t < UC_; t++) u += MO[(long)(NCAND + b * UC_ + t) * 128 + d];
  u *= (1.0f / UC_);
  __shared__ float red[2];
  for (int s = 0; s < S_; s++) {
    float p = MO[(long)(b * S_ + s) * 128 + d] * u;
#pragma unroll
    for (int o = 32; o > 0; o >>= 1) p += __shfl_down(p, o, 64);
    if ((d & 63) == 0) red[d >> 6] = p;
    __syncthreads();
    if (d == 0) {
      float v = red[0] + red[1];
      if (bf)
        ((__hip_bfloat16*)out)[b * S_ + s] = __float2bfloat16(v);
      else
        ((float*)out)[b * S_ + s] = v;
    }
    __syncthreads();
  }
}

extern "C" void kernel_launch(void* const* d_in, const int* in_sizes, int n_in,
                              void* d_out, int out_size, void* d_ws, size_t ws_size,
                              hipStream_t stream) {
  (void)in_sizes; (void)n_in; (void)out_size; (void)ws_size;
  const void* titles = d_in[0];
  const void* ent    = d_in[1];
  const void* rel    = d_in[2];
  const void* Wnc1 = d_in[3];  const void* bnc1 = d_in[4];
  const void* Wnc2 = d_in[5];  const void* bnc2 = d_in[6];
  const void* Wanc = d_in[7];  const void* banc = d_in[8];
  const void* Waw1 = d_in[9];  const void* baw1 = d_in[10];
  const void* Waw2 = d_in[11]; const void* baw2 = d_in[12];
  const void* Wm1  = d_in[13]; const void* bm1  = d_in[14];
  const void* Wm2  = d_in[15]; const void* bm2  = d_in[16];
  const int* cand  = (const int*)d_in[17];
  const int* clk   = (const int*)d_in[18];
  const int* canda = (const int*)d_in[19];
  const int* clka  = (const int*)d_in[20];
  const int* eadj  = (const int*)d_in[21];
  const int* radj  = (const int*)d_in[22];
  float* ws = (float*)d_ws;

  k_detect<<<1, 256, 0, stream>>>(ent, (int*)d_ws);
  k_prep<<<256, 256, 0, stream>>>(Wnc1, bnc1, Wnc2, bnc2, Wanc, banc, Waw1, baw1,
                                  Waw2, baw2, Wm1, bm1, Wm2, bm2, rel, ws);
  k_news<<<NNEWS / 8, 128, 0, stream>>>(titles, cand, clk, ws);
  k_gather<<<NANCH / 8, 256, 0, stream>>>(ent, canda, clka, eadj, radj, ws);
  k_anchor<<<NNEWS / 8, 256, 0, stream>>>(ws);
  k_mlp<<<NNEWS / 16, 256, 0, stream>>>(ws);
  k_score<<<B_, 128, 0, stream>>>(ws, d_out);
}

// Round 8
// 239.691 us; speedup vs baseline: 6.9627x; 1.2333x over previous
//
#include <hip/hip_runtime.h>
#include <hip/hip_bf16.h>

// ---------------------------------------------------------------------------
// Recommender pipeline.
//  K0 detect : bf16-vs-f32 flag in ws[0]
//  K1 prep   : weights -> ws; K-PACKED f32 for news/mlp GEMMs; Wanc/Waw1
//              SPLIT-BF16 frag-packed [kt][n][16] hi/lo for MFMA.
//  K2 news   : news_e = tanh(elu(title@W1^T+b)@W2^T+b)        [3520,128]
//  K3 gather : X[n] = [ent[node], sum_k(ent[adj]+rel[radj])]  [70400,256]
//              written split-bf16 in MFMA A-FRAG ORDER [rt][kt][kh][ln][8]
//              via LDS transpose (32 rows/block) -> k_anchor A-loads are
//              single coalesced 1KB bursts (R7 had 64-line gathers).
//  K4 anchor : MFMA (v_mfma_f32_32x32x16_bf16) 3-term split-bf16.
//              R7 post-mortem: 124us, all pipes <17%, occ 9.9% -> latency
//              bound (uncoalesced A + 1 block/CU). R8: frag-ordered A +
//              LGp/LG moved to global scratch (MO region, dead until k_mlp)
//              -> LDS exactly 80KB -> 2 blocks/CU.
//  K5 mlp    : elu(elu([news_e,AE]@Wm1^T+b)@Wm2^T+b)          [3520,128]
//  K6 score  : user mean + dot                                 [64,5]
// ---------------------------------------------------------------------------

#define B_ 64
#define S_ 5
#define UC_ 50
#define A_ 20
#define NCAND 320
#define NCLK 3200
#define NNEWS 3520
#define NANCH 70400

// ws layout (float indices)
static constexpr long OFF_WNC1P = 64;        // [192][128][4] f32
static constexpr long OFF_BNC1  = 98368;
static constexpr long OFF_WNC2P = 98496;     // [32][128][4] f32
static constexpr long OFF_BNC2  = 114880;
static constexpr long OFF_WANCP = 115008;    // [16kt][128n][16k] bf16 hi + lo (65536 ushort)
static constexpr long OFF_BANC  = 147776;
static constexpr long OFF_WAW1P = 147904;    // [8kt][128n][16k] bf16 hi + lo (32768 ushort)
static constexpr long OFF_BAW1  = 164288;
static constexpr long OFF_WAW2  = 164416;    // [128]
static constexpr long OFF_BAW2  = 164544;    // [1]
static constexpr long OFF_WM1P  = 164548;    // [64][128][4] f32
static constexpr long OFF_BM1   = 197316;
static constexpr long OFF_WM2P  = 197444;    // [32][128][4] f32
static constexpr long OFF_BM2   = 213828;
static constexpr long OFF_REL   = 213956;    // [100][128] f32
static constexpr long OFF_AE    = 226756;    // [3520][128] f32
static constexpr long OFF_NE    = 677316;    // [3520][128] f32
static constexpr long OFF_MO    = 1127876;   // [3520][128] f32 (k_anchor LG scratch, then k_mlp out)
static constexpr long OFF_X     = 1578436;   // XH[2200][8192] + XL[2200][8192] ushort frag-order
// total ~19.6M floats = 78.4 MB

typedef __attribute__((ext_vector_type(8))) short short8v;   // 8 bf16 = 4 VGPR
typedef __attribute__((ext_vector_type(16))) float f32x16;   // MFMA 32x32 acc

__device__ __forceinline__ float ldf(const void* p, long i, int bf) {
  if (bf) {
    unsigned int u = (unsigned int)((const unsigned short*)p)[i];
    u <<= 16;
    return __uint_as_float(u);
  }
  return ((const float*)p)[i];
}

// 4 consecutive elems starting at i (i % 4 == 0)
__device__ __forceinline__ float4 ldf4(const void* p, long i, int bf) {
  float4 f;
  if (bf) {
    const unsigned short* q = (const unsigned short*)p + i;
    uint2 u = *(const uint2*)q;
    f.x = __uint_as_float(u.x << 16);
    f.y = __uint_as_float(u.x & 0xffff0000u);
    f.z = __uint_as_float(u.y << 16);
    f.w = __uint_as_float(u.y & 0xffff0000u);
  } else {
    f = *(const float4*)((const float*)p + i);
  }
  return f;
}

__device__ __forceinline__ float eluf(float v) { return v > 0.f ? v : expm1f(v); }

// split f32 v into hi (truncated bf16 bits) + lo (RNE bf16 of remainder)
__device__ __forceinline__ void splitbf(float v, unsigned short& hi, unsigned short& lo) {
  unsigned int b = __float_as_uint(v);
  hi = (unsigned short)(b >> 16);
  float rm = v - __uint_as_float(b & 0xffff0000u);
  unsigned int rb = __float_as_uint(rm);
  lo = (unsigned short)((rb + 0x7fffu + ((rb >> 16) & 1u)) >> 16);
}

__device__ __forceinline__ float bfh(unsigned short u) {
  return __uint_as_float((unsigned int)u << 16);
}

// ---- K0: dtype detect -----------------------------------------------------
__global__ void k_detect(const void* ent, int* flag) {
  __shared__ int cnt;
  if (threadIdx.x == 0) cnt = 0;
  __syncthreads();
  unsigned short u = ((const unsigned short*)ent)[threadIdx.x];
  int e = (u >> 7) & 0xFF;
  int ok = (e >= 107 && e <= 146) ? 1 : 0;
  atomicAdd(&cnt, ok);
  __syncthreads();
  if (threadIdx.x == 0) *flag = (cnt >= 200) ? 1 : 0;
}

// ---- K1: convert weights --------------------------------------------------
// MD 0: plain f32. MD 2: f32 K-packed [k/4][128][4]. MD 3: split-bf16 MFMA
// B-frag pack [kt][n][16k] hi then lo.
__global__ __launch_bounds__(256) void k_prep(
    const void* s0, const void* s1, const void* s2, const void* s3,
    const void* s4, const void* s5, const void* s6, const void* s7,
    const void* s8, const void* s9, const void* s10, const void* s11,
    const void* s12, const void* s13, const void* s14, float* ws) {
  const int bf = ((const int*)ws)[0];
  const void* srcs[15] = {s0,s1,s2,s3,s4,s5,s6,s7,s8,s9,s10,s11,s12,s13,s14};
  const int R[15] = {128,128,128,128,128,128,128,128,1,  1,  128,128,128,128,100};
  const int C[15] = {768,1,  128,1,  256,1,  128,1,  128,1,  256,1,  128,1,  128};
  const int MD[15]= {2,  0,  2,  0,  3,  0,  3,  0,  0,  0,  2,  0,  2,  0,  0};
  const long OFF[15] = {OFF_WNC1P,OFF_BNC1,OFF_WNC2P,OFF_BNC2,OFF_WANCP,OFF_BANC,
                        OFF_WAW1P,OFF_BAW1,OFF_WAW2,OFF_BAW2,OFF_WM1P,OFF_BM1,
                        OFF_WM2P,OFF_BM2,OFF_REL};
  const long total = 226689;
  for (long idx = (long)blockIdx.x * blockDim.x + threadIdx.x; idx < total;
       idx += (long)gridDim.x * blockDim.x) {
    long rem = idx;
    int s = 0;
    while (rem >= (long)R[s] * C[s]) { rem -= (long)R[s] * C[s]; s++; }
    float v = ldf(srcs[s], rem, bf);
    if (MD[s] == 2) {
      long r = rem / C[s], c = rem - r * C[s];
      ws[OFF[s] + (c >> 2) * 512 + r * 4 + (c & 3)] = v;
    } else if (MD[s] == 3) {
      long r = rem / C[s], c = rem - r * C[s];   // r = out n, c = k
      unsigned short hi, lo;
      splitbf(v, hi, lo);
      unsigned short* H = (unsigned short*)(ws + OFF[s]);
      unsigned short* L = H + (s == 4 ? 32768 : 16384);
      long id2 = ((c >> 4) * 128 + r) * 16 + (c & 15);
      H[id2] = hi;
      L[id2] = lo;
    } else {
      ws[OFF[s] + rem] = v;
    }
  }
}

// ---- K2: news title MLP (128 thr, 8 rows, acc[8]) ------------------------
__global__ __launch_bounds__(128) void k_news(const void* titles, const int* cand,
                                              const int* clk, float* ws) {
  const int bf = ((const int*)ws)[0];
  __shared__ __align__(16) float t[8][768];
  __shared__ __align__(16) float h1[8][128];
  int tid = threadIdx.x;
  long r0 = (long)blockIdx.x * 8;
  for (int x = tid * 4; x < 8 * 768; x += 128 * 4) {
    int c = x / 768, k = x - c * 768;
    long i = r0 + c;
    int id = (i < NCAND) ? cand[i] : clk[i - NCAND];
    *(float4*)&t[c][k] = ldf4(titles, (long)id * 768 + k, bf);
  }
  __syncthreads();
  int j = tid;
  const float4* W1 = (const float4*)(ws + OFF_WNC1P);
  float acc[8];
#pragma unroll
  for (int c = 0; c < 8; c++) acc[c] = 0.f;
  for (int k4 = 0; k4 < 192; k4++) {
    float4 w = W1[k4 * 128 + j];
#pragma unroll
    for (int c = 0; c < 8; c++) {
      const float4 xv = *(const float4*)&t[c][k4 * 4];
      acc[c] += w.x * xv.x + w.y * xv.y + w.z * xv.z + w.w * xv.w;
    }
  }
  float b1 = ws[OFF_BNC1 + j];
#pragma unroll
  for (int c = 0; c < 8; c++) h1[c][j] = eluf(acc[c] + b1);
  __syncthreads();
  const float4* W2 = (const float4*)(ws + OFF_WNC2P);
  float a2[8];
#pragma unroll
  for (int c = 0; c < 8; c++) a2[c] = 0.f;
  for (int k4 = 0; k4 < 32; k4++) {
    float4 w = W2[k4 * 128 + j];
#pragma unroll
    for (int c = 0; c < 8; c++) {
      const float4 xv = *(const float4*)&h1[c][k4 * 4];
      a2[c] += w.x * xv.x + w.y * xv.y + w.z * xv.z + w.w * xv.w;
    }
  }
  float b2 = ws[OFF_BNC2 + j];
  float* NE = ws + OFF_NE;
#pragma unroll
  for (int c = 0; c < 8; c++) NE[(r0 + c) * 128 + j] = tanhf(a2[c] + b2);
}

// ---- K3: gather -> split-bf16 X in MFMA A-frag order ----------------------
// 32 rows/block (grid 2200), 256 thr = 8 groups x 32 lanes, 4 rows/group.
// Rows staged hi/lo in LDS [32][264] (16B-aligned rows), then written out
// thread-linear in frag order: XH[rt*8192 + (kt*2+kh)*256 + ln*8 + e].
__global__ __launch_bounds__(256) void k_gather(const void* ent, const int* canda,
                                                const int* clka, const int* eadj,
                                                const int* radj, float* ws) {
  const int bf = ((const int*)ws)[0];
  __shared__ __align__(16) unsigned short XbH[32][264];
  __shared__ __align__(16) unsigned short XbL[32][264];
  int tid = threadIdx.x;
  int lane = tid & 31;
  int grp = tid >> 5;
  const float* relf = ws + OFF_REL;
  for (int i = 0; i < 4; ++i) {
    int row = grp * 4 + i;
    long n = (long)blockIdx.x * 32 + row;
    int node = (n < (long)NCAND * A_) ? canda[n] : clka[n - (long)NCAND * A_];
    int idx = 0;
    if (lane < 10) idx = eadj[(long)node * 10 + lane];
    else if (lane < 20) idx = radj[(long)node * 10 + (lane - 10)];
    int an[10], rn[10];
#pragma unroll
    for (int k = 0; k < 10; k++) {
      an[k] = __shfl(idx, k, 32);
      rn[k] = __shfl(idx, k + 10, 32);
    }
    float4 x1 = ldf4(ent, (long)node * 128 + lane * 4, bf);
    float4 acc = {0.f, 0.f, 0.f, 0.f};
#pragma unroll
    for (int k = 0; k < 10; k++) {
      float4 e = ldf4(ent, (long)an[k] * 128 + lane * 4, bf);
      const float4 r = *(const float4*)&relf[(long)rn[k] * 128 + lane * 4];
      acc.x += e.x + r.x;
      acc.y += e.y + r.y;
      acc.z += e.z + r.z;
      acc.w += e.w + r.w;
    }
    ushort4 h4, l4;
    splitbf(x1.x, h4.x, l4.x); splitbf(x1.y, h4.y, l4.y);
    splitbf(x1.z, h4.z, l4.z); splitbf(x1.w, h4.w, l4.w);
    *(ushort4*)&XbH[row][lane * 4] = h4;
    *(ushort4*)&XbL[row][lane * 4] = l4;
    splitbf(acc.x, h4.x, l4.x); splitbf(acc.y, h4.y, l4.y);
    splitbf(acc.z, h4.z, l4.z); splitbf(acc.w, h4.w, l4.w);
    *(ushort4*)&XbH[row][128 + lane * 4] = h4;
    *(ushort4*)&XbL[row][128 + lane * 4] = l4;
  }
  __syncthreads();
  unsigned short* XH = (unsigned short*)(ws + OFF_X);
  unsigned short* XL = XH + (size_t)NANCH * 256;
  long base = (long)blockIdx.x * 8192;
  for (int c = tid; c < 1024; c += 256) {  // 16B chunks: c = kt2h*32 + ln
    int ln = c & 31, kt2h = c >> 5;
    *(uint4*)&XH[base + (long)c * 8] = *(const uint4*)&XbH[ln][kt2h * 8];
    *(uint4*)&XL[base + (long)c * 8] = *(const uint4*)&XbL[ln][kt2h * 8];
  }
}

// ---- K4: MFMA anchor GEMMs + softmax -------------------------------------
// block = 8 news = 160 rows (5 M-tiles), 256 thr = 4 waves; wave w = N-tile
// w (cols w*32..+31). A-frag loads fully coalesced via K3's frag order.
// LDS = Hhi+Hlo = exactly 80KB -> 2 blocks/CU. Logit partials go to global
// scratch (MO region, dead until k_mlp). C/D map (m74/m101): col = l&31,
// row = (reg&3) + 8*(reg>>2) + 4*(l>>5).
__global__ __launch_bounds__(256, 2) void k_anchor(float* ws) {
  __shared__ __align__(16) unsigned short Hhi[160][128];  // 40 KB
  __shared__ __align__(16) unsigned short Hlo[160][128];  // 40 KB
  int tid = threadIdx.x;
  int lane = tid & 63, wv = tid >> 6;
  int ln = lane & 31, kh = lane >> 5;
  int col = (wv << 5) + ln;

  const unsigned short* XH = (const unsigned short*)(ws + OFF_X);
  const unsigned short* XL = XH + (size_t)NANCH * 256;
  const unsigned short* WAH = (const unsigned short*)(ws + OFF_WANCP);
  const unsigned short* WAL = WAH + 32768;
  const unsigned short* W1H = (const unsigned short*)(ws + OFF_WAW1P);
  const unsigned short* W1L = W1H + 16384;
  float* LGs = ws + OFF_MO + (long)blockIdx.x * 640;  // [4][160] per-wave partials

  // --- Stage B: H = tanh(X @ Wanc^T + b), [160,256]@[256->128] ---
  {
    f32x16 acc[5] = {};
    for (int kt = 0; kt < 16; ++kt) {
      long wi = ((long)(kt * 128 + col) << 4) + (kh << 3);
      short8v bhi = *(const short8v*)(WAH + wi);
      short8v blo = *(const short8v*)(WAL + wi);
#pragma unroll
      for (int mt = 0; mt < 5; ++mt) {
        long ai = ((long)(blockIdx.x * 5 + mt) << 13) + ((kt * 2 + kh) << 8) + (ln << 3);
        short8v ahi = *(const short8v*)(XH + ai);
        short8v alo = *(const short8v*)(XL + ai);
        acc[mt] = __builtin_amdgcn_mfma_f32_32x32x16_bf16(ahi, bhi, acc[mt], 0, 0, 0);
        acc[mt] = __builtin_amdgcn_mfma_f32_32x32x16_bf16(ahi, blo, acc[mt], 0, 0, 0);
        acc[mt] = __builtin_amdgcn_mfma_f32_32x32x16_bf16(alo, bhi, acc[mt], 0, 0, 0);
      }
    }
    float bc = ws[OFF_BANC + col];
#pragma unroll
    for (int mt = 0; mt < 5; ++mt)
#pragma unroll
      for (int j = 0; j < 16; ++j) {
        int r = mt * 32 + (j & 3) + ((j >> 2) << 3) + (kh << 2);
        float h = tanhf(acc[mt][j] + bc);
        unsigned short hi, lo;
        splitbf(h, hi, lo);
        int sc = col ^ ((r & 7) << 3);   // T2 XOR swizzle (16B granules)
        Hhi[r][sc] = hi;
        Hlo[r][sc] = lo;
      }
  }
  __syncthreads();

  // --- Stage C: logits = elu(H@Waw1^T+b1)@w2 + b2, [160,128]@[128->128] ---
  {
    f32x16 ac[5] = {};
    for (int kt = 0; kt < 8; ++kt) {
      long wi = ((long)(kt * 128 + col) << 4) + (kh << 3);
      short8v bhi = *(const short8v*)(W1H + wi);
      short8v blo = *(const short8v*)(W1L + wi);
#pragma unroll
      for (int mt = 0; mt < 5; ++mt) {
        int rr = mt * 32 + ln;
        int kb = (kt * 16 + (kh << 3)) ^ ((rr & 7) << 3);
        short8v ahi = *(const short8v*)&Hhi[rr][kb];
        short8v alo = *(const short8v*)&Hlo[rr][kb];
        ac[mt] = __builtin_amdgcn_mfma_f32_32x32x16_bf16(ahi, bhi, ac[mt], 0, 0, 0);
        ac[mt] = __builtin_amdgcn_mfma_f32_32x32x16_bf16(ahi, blo, ac[mt], 0, 0, 0);
        ac[mt] = __builtin_amdgcn_mfma_f32_32x32x16_bf16(alo, bhi, ac[mt], 0, 0, 0);
      }
    }
    float b1c = ws[OFF_BAW1 + col];
    float w2c = ws[OFF_WAW2 + col];
#pragma unroll
    for (int mt = 0; mt < 5; ++mt)
#pragma unroll
      for (int j = 0; j < 16; ++j) {
        int r = mt * 32 + (j & 3) + ((j >> 2) << 3) + (kh << 2);
        float v = eluf(ac[mt][j] + b1c) * w2c;
        v += __shfl_xor(v, 16);
        v += __shfl_xor(v, 8);
        v += __shfl_xor(v, 4);
        v += __shfl_xor(v, 2);
        v += __shfl_xor(v, 1);
        if (ln == 0) LGs[wv * 160 + r] = v;   // lanes 0 and 32 (different r)
      }
  }
  __threadfence_block();
  __syncthreads();

  // --- Stage D: per-news softmax over 20 anchors + weighted sum ---
  {
    int g = tid >> 5, l32 = tid & 31, ar = g * 20;
    float bw2 = ws[OFF_BAW2];
    float e[20], mx = -1e30f;
#pragma unroll
    for (int a = 0; a < 20; ++a) {
      int rr = ar + a;
      e[a] = LGs[rr] + LGs[160 + rr] + LGs[320 + rr] + LGs[480 + rr] + bw2;
      mx = fmaxf(mx, e[a]);
    }
    float s = 0.f;
#pragma unroll
    for (int a = 0; a < 20; ++a) { e[a] = expf(e[a] - mx); s += e[a]; }
    float inv = 1.0f / s;
    float o0 = 0.f, o1 = 0.f, o2 = 0.f, o3 = 0.f;
#pragma unroll
    for (int a = 0; a < 20; ++a) {
      int rr = ar + a, sw = (rr & 7) << 3;
      float w = e[a];
      int d0 = l32 ^ sw, d1 = (l32 + 32) ^ sw, d2 = (l32 + 64) ^ sw, d3 = (l32 + 96) ^ sw;
      o0 += w * (bfh(Hhi[rr][d0]) + bfh(Hlo[rr][d0]));
      o1 += w * (bfh(Hhi[rr][d1]) + bfh(Hlo[rr][d1]));
      o2 += w * (bfh(Hhi[rr][d2]) + bfh(Hlo[rr][d2]));
      o3 += w * (bfh(Hhi[rr][d3]) + bfh(Hlo[rr][d3]));
    }
    float* AE = ws + OFF_AE;
    long ro = ((long)blockIdx.x * 8 + g) * 128;
    AE[ro + l32]      = o0 * inv;
    AE[ro + l32 + 32] = o1 * inv;
    AE[ro + l32 + 64] = o2 * inv;
    AE[ro + l32 + 96] = o3 * inv;
  }
}

// ---- K5: final MLP --------------------------------------------------------
__global__ __launch_bounds__(256) void k_mlp(float* ws) {
  __shared__ __align__(16) float xt[16][256];
  __shared__ __align__(16) float h1[16][128];
  int tid = threadIdx.x;
  long r0 = (long)blockIdx.x * 16;
  const float* NE = ws + OFF_NE;
  const float* AE = ws + OFF_AE;
  for (int x = tid; x < 16 * 256; x += 256) {
    int c = x >> 8, k = x & 255;
    xt[c][k] = (k < 128) ? NE[(r0 + c) * 128 + k] : AE[(r0 + c) * 128 + (k - 128)];
  }
  __syncthreads();
  int j = tid & 127, half = tid >> 7;
  const float4* W1 = (const float4*)(ws + OFF_WM1P);
  float acc[8];
#pragma unroll
  for (int c = 0; c < 8; c++) acc[c] = 0.f;
  for (int k4 = 0; k4 < 64; k4++) {
    float4 w = W1[k4 * 128 + j];
#pragma unroll
    for (int c = 0; c < 8; c++) {
      const float4 xv = *(const float4*)&xt[half * 8 + c][k4 * 4];
      acc[c] += w.x * xv.x + w.y * xv.y + w.z * xv.z + w.w * xv.w;
    }
  }
  float b1 = ws[OFF_BM1 + j];
#pragma unroll
  for (int c = 0; c < 8; c++) h1[half * 8 + c][j] = eluf(acc[c] + b1);
  __syncthreads();
  const float4* W2 = (const float4*)(ws + OFF_WM2P);
  float a2[8];
#pragma unroll
  for (int c = 0; c < 8; c++) a2[c] = 0.f;
  for (int k4 = 0; k4 < 32; k4++) {
    float4 w = W2[k4 * 128 + j];
#pragma unroll
    for (int c = 0; c < 8; c++) {
      const float4 xv = *(const float4*)&h1[half * 8 + c][k4 * 4];
      a2[c] += w.x * xv.x + w.y * xv.y + w.z * xv.z + w.w * xv.w;
    }
  }
  float b2 = ws[OFF_BM2 + j];
  float* MO = ws + OFF_MO;
#pragma unroll
  for (int c = 0; c < 8; c++) MO[(r0 + half * 8 + c) * 128 + j] = eluf(a2[c] + b2);
}

// ---- K6: user mean + scores ----------------------------------------------
__global__ __launch_bounds__(128) void k_score(const float* ws, void* out) {
  const int bf = ((const int*)ws)[0];
  int b = blockIdx.x;
  int d = threadIdx.x;
  const float* MO = ws + OFF_MO;
  float u = 0.f;
  for (int t = 0; t < UC_; t++) u += MO[(long)(NCAND + b * UC_ + t) * 128 + d];
  u *= (1.0f / UC_);
  __shared__ float red[2];
  for (int s = 0; s < S_; s++) {
    float p = MO[(long)(b * S_ + s) * 128 + d] * u;
#pragma unroll
    for (int o = 32; o > 0; o >>= 1) p += __shfl_down(p, o, 64);
    if ((d & 63) == 0) red[d >> 6] = p;
    __syncthreads();
    if (d == 0) {
      float v = red[0] + red[1];
      if (bf)
        ((__hip_bfloat16*)out)[b * S_ + s] = __float2bfloat16(v);
      else
        ((float*)out)[b * S_ + s] = v;
    }
    __syncthreads();
  }
}

extern "C" void kernel_launch(void* const* d_in, const int* in_sizes, int n_in,
                              void* d_out, int out_size, void* d_ws, size_t ws_size,
                              hipStream_t stream) {
  (void)in_sizes; (void)n_in; (void)out_size; (void)ws_size;
  const void* titles = d_in[0];
  const void* ent    = d_in[1];
  const void* rel    = d_in[2];
  const void* Wnc1 = d_in[3];  const void* bnc1 = d_in[4];
  const void* Wnc2 = d_in[5];  const void* bnc2 = d_in[6];
  const void* Wanc = d_in[7];  const void* banc = d_in[8];
  const void* Waw1 = d_in[9];  const void* baw1 = d_in[10];
  const void* Waw2 = d_in[11]; const void* baw2 = d_in[12];
  const void* Wm1  = d_in[13]; const void* bm1  = d_in[14];
  const void* Wm2  = d_in[15]; const void* bm2  = d_in[16];
  const int* cand  = (const int*)d_in[17];
  const int* clk   = (const int*)d_in[18];
  const int* canda = (const int*)d_in[19];
  const int* clka  = (const int*)d_in[20];
  const int* eadj  = (const int*)d_in[21];
  const int* radj  = (const int*)d_in[22];
  float* ws = (float*)d_ws;

  k_detect<<<1, 256, 0, stream>>>(ent, (int*)d_ws);
  k_prep<<<256, 256, 0, stream>>>(Wnc1, bnc1, Wnc2, bnc2, Wanc, banc, Waw1, baw1,
                                  Waw2, baw2, Wm1, bm1, Wm2, bm2, rel, ws);
  k_news<<<NNEWS / 8, 128, 0, stream>>>(titles, cand, clk, ws);
  k_gather<<<NANCH / 32, 256, 0, stream>>>(ent, canda, clka, eadj, radj, ws);
  k_anchor<<<NNEWS / 8, 256, 0, stream>>>(ws);
  k_mlp<<<NNEWS / 16, 256, 0, stream>>>(ws);
  k_score<<<B_, 128, 0, stream>>>(ws, d_out);
}